// Round 2
// baseline (952.999 us; speedup 1.0000x reference)
//
#include <hip/hip_runtime.h>

#define N_IN_CH 256
#define N_OUT_CH 64
#define XPAD 264    // 256 + 8 ushort pad: row stride 528 B -> conflict-free b128
#define BROW 128    // rows per bucket
#define NBK 1024    // max buckets: ceil(100000/128) = 782
#define B1_E 8192   // edges per bin_kernel block

typedef __attribute__((ext_vector_type(8))) short short8;
typedef __attribute__((ext_vector_type(4))) float f32x4;

__device__ inline ushort f2bf(float f) {
    unsigned u = __float_as_uint(f);
    return (ushort)((u + 0x7FFFu + ((u >> 16) & 1u)) >> 16);   // RTNE
}
__device__ inline float bf2f(ushort u) {
    return __uint_as_float(((unsigned)u) << 16);
}

// --- Kernel 1: W [64][256] fp32 -> bf16 ---
__global__ void wbf_kernel(const float* __restrict__ W, ushort* __restrict__ Wbf) {
    int i = blockIdx.x * blockDim.x + threadIdx.x;
    if (i < N_OUT_CH * N_IN_CH) Wbf[i] = f2bf(W[i]);
}

// --- Kernel 2: Xp = X @ W^T via bf16 MFMA; 64 rows/block, K=256 in one shot ---
__global__ __launch_bounds__(256) void mfma_gemm_kernel(const float* __restrict__ X,
        const ushort* __restrict__ Wbf, ushort* __restrict__ Xp, int nrows) {
    __shared__ ushort Xs[64 * XPAD];
    __shared__ ushort Ws[64 * XPAD];

    const int tid = threadIdx.x;
    const int row0 = blockIdx.x * 64;

    #pragma unroll
    for (int it = 0; it < 16; ++it) {
        int f = it * 256 + tid;
        int n = f >> 6, c4 = f & 63;
        ushort4 v = *(const ushort4*)&Wbf[n * N_IN_CH + c4 * 4];
        *(ushort4*)&Ws[n * XPAD + c4 * 4] = v;
    }
    #pragma unroll
    for (int it = 0; it < 16; ++it) {
        int f = it * 256 + tid;
        int r = f >> 6, c4 = f & 63;
        int gr = row0 + r;
        float4 x = make_float4(0.f, 0.f, 0.f, 0.f);
        if (gr < nrows) x = *(const float4*)&X[(size_t)gr * N_IN_CH + c4 * 4];
        ushort4 u;
        u.x = f2bf(x.x); u.y = f2bf(x.y); u.z = f2bf(x.z); u.w = f2bf(x.w);
        *(ushort4*)&Xs[r * XPAD + c4 * 4] = u;
    }
    __syncthreads();

    const int wave = tid >> 6, lane = tid & 63;
    const int ml = lane & 15, quad = lane >> 4;

    const ushort* abase = &Xs[(wave * 16 + ml) * XPAD + quad * 8];
    short8 a[8];
    #pragma unroll
    for (int kt = 0; kt < 8; ++kt) a[kt] = *(const short8*)&abase[kt * 32];

    const ushort* bbase = &Ws[ml * XPAD + quad * 8];

    #pragma unroll
    for (int nt = 0; nt < 4; ++nt) {
        f32x4 acc = {0.f, 0.f, 0.f, 0.f};
        #pragma unroll
        for (int kt = 0; kt < 8; ++kt) {
            short8 b = *(const short8*)&bbase[nt * 16 * XPAD + kt * 32];
            acc = __builtin_amdgcn_mfma_f32_16x16x32_bf16(a[kt], b, acc, 0, 0, 0);
        }
        #pragma unroll
        for (int reg = 0; reg < 4; ++reg) {
            int gr = row0 + wave * 16 + quad * 4 + reg;
            if (gr < nrows)
                Xp[(size_t)gr * N_OUT_CH + nt * 16 + ml] = f2bf(acc[reg]);
        }
    }
}

// --- Bucket histogram: nb bins (row >> 7), LDS-staged ---
__global__ __launch_bounds__(256) void bhist_kernel(const int* __restrict__ rows,
        int* __restrict__ bcnt, int nnz, int nb) {
    __shared__ int h[NBK];
    for (int i = threadIdx.x; i < nb; i += 256) h[i] = 0;
    __syncthreads();
    for (int e = blockIdx.x * 256 + threadIdx.x; e < nnz; e += gridDim.x * 256)
        atomicAdd(&h[rows[e] >> 7], 1);
    __syncthreads();
    for (int i = threadIdx.x; i < nb; i += 256) {
        int c = h[i];
        if (c) atomicAdd(&bcnt[i], c);
    }
}

// --- Bucket exclusive scan (single block, <=1024 buckets, 4/thread) ---
__global__ __launch_bounds__(256) void bscan_kernel(const int* __restrict__ bcnt,
        int* __restrict__ bstart, int* __restrict__ bcur, int nb, int nnz) {
    __shared__ int sh[256];
    int t = threadIdx.x;
    int c[4];
    #pragma unroll
    for (int j = 0; j < 4; ++j) {
        int i = t * 4 + j;
        c[j] = (i < nb) ? bcnt[i] : 0;
    }
    int s = c[0] + c[1] + c[2] + c[3];
    sh[t] = s;
    __syncthreads();
    #pragma unroll
    for (int d = 1; d < 256; d <<= 1) {
        int a = (t >= d) ? sh[t - d] : 0;
        __syncthreads();
        sh[t] += a;
        __syncthreads();
    }
    int base = sh[t] - s;   // exclusive over thread chunks
    #pragma unroll
    for (int j = 0; j < 4; ++j) {
        int i = t * 4 + j;
        if (i < nb) { bstart[i] = base; bcur[i] = base; }
        base += c[j];
    }
    if (t == 0) bstart[nb] = nnz;
}

// --- B1: bin-append. Per block: LDS count -> 1 atomic per bucket -> contiguous
//     per-(block,bucket) segment writes of (row_local<<17|col, val). ---
__global__ __launch_bounds__(256) void bin_kernel(const int* __restrict__ rows,
        const int* __restrict__ cols, const float* __restrict__ vals,
        int* __restrict__ bcur, int2* __restrict__ colbuf, int nnz, int nb) {
    __shared__ int cnt[NBK];
    __shared__ int base[NBK];
    const int t = threadIdx.x;
    const int e0 = blockIdx.x * B1_E;

    for (int i = t; i < nb; i += 256) cnt[i] = 0;
    __syncthreads();
    #pragma unroll
    for (int it = 0; it < B1_E / 256; ++it) {
        int e = e0 + it * 256 + t;
        if (e < nnz) atomicAdd(&cnt[rows[e] >> 7], 1);
    }
    __syncthreads();
    for (int i = t; i < nb; i += 256) {
        int c = cnt[i];
        base[i] = c ? atomicAdd(&bcur[i], c) : 0;
        cnt[i] = 0;
    }
    __syncthreads();
    #pragma unroll
    for (int it = 0; it < B1_E / 256; ++it) {
        int e = e0 + it * 256 + t;
        if (e < nnz) {
            int r = rows[e];
            int b = r >> 7;
            int pos = base[b] + atomicAdd(&cnt[b], 1);
            int2 cv;
            cv.x = cols[e] | ((r & 127) << 17);   // col < 2^17, row_local 7 bits
            cv.y = __float_as_int(vals[e]);
            colbuf[pos] = cv;
        }
    }
}

// --- Fused bucket SpMM: one block per bucket; LDS [128][64] f32 accumulator,
//     ds_add_f32 per edge, single coalesced writeout. Replaces the row-sort
//     pass + CSR SpMM entirely. ---
__global__ __launch_bounds__(512) void bspmm_kernel(const int* __restrict__ bstart,
        const int2* __restrict__ colbuf, const ushort* __restrict__ Xp,
        float* __restrict__ out, int nrows) {
    __shared__ float acc[BROW * 64];   // 32 KB
    const int b = blockIdx.x, t = threadIdx.x;
    const int bs = bstart[b], be = bstart[b + 1];

    #pragma unroll
    for (int i = t; i < BROW * 64; i += 512) acc[i] = 0.f;
    __syncthreads();

    const int wave = t >> 6, lane = t & 63;
    const int U = 8;

    for (int base = bs + wave * U; base < be; base += 8 * U) {
        int2 cv[U];
        #pragma unroll
        for (int j = 0; j < U; ++j) {
            int e = base + j;
            int2 v; v.x = 0; v.y = 0;
            if (e < be) v = colbuf[e];
            cv[j] = v;
        }
        float x[U];
        #pragma unroll
        for (int j = 0; j < U; ++j)
            x[j] = bf2f(Xp[(size_t)(cv[j].x & 0x1FFFF) * N_OUT_CH + lane]);
        #pragma unroll
        for (int j = 0; j < U; ++j)
            atomicAdd(&acc[((cv[j].x >> 17) & 127) * 64 + lane],
                      __int_as_float(cv[j].y) * x[j]);
    }
    __syncthreads();

    const int row0 = b * BROW;
    #pragma unroll
    for (int i4 = t; i4 < BROW * 16; i4 += 512) {
        int i = i4 * 4;
        int r = row0 + (i >> 6);
        if (r < nrows)
            *(float4*)&out[(size_t)r * N_OUT_CH + (i & 63)] = *(const float4*)&acc[i];
    }
}

// --- Fallback atomic SpMM (ws too small — not expected) ---
__global__ __launch_bounds__(256) void spmm_atomic_kernel(const int* __restrict__ rows,
        const int* __restrict__ cols, const float* __restrict__ vals,
        const ushort* __restrict__ Xp, float* __restrict__ out, int nnz) {
    int t = blockIdx.x * blockDim.x + threadIdx.x;
    int e = t >> 6;
    int c = t & 63;
    if (e < nnz) {
        atomicAdd(&out[(size_t)rows[e] * N_OUT_CH + c],
                  vals[e] * bf2f(Xp[(size_t)cols[e] * N_OUT_CH + c]));
    }
}

extern "C" void kernel_launch(void* const* d_in, const int* in_sizes, int n_in,
                              void* d_out, int out_size, void* d_ws, size_t ws_size,
                              hipStream_t stream) {
    const float* X      = (const float*)d_in[2];
    const float* W      = (const float*)d_in[3];
    const int*   L_rows = (const int*)d_in[4];
    const int*   L_cols = (const int*)d_in[5];
    const float* L_vals = (const float*)d_in[6];
    float* out = (float*)d_out;

    const int nrows = in_sizes[2] / N_IN_CH;   // 100000
    const int nnz   = in_sizes[4];             // 1600000
    const int nb    = (nrows + BROW - 1) / BROW;   // 782 buckets

    // workspace layout (8B-aligned)
    size_t off_wbf = 0;                                             // 32 KB
    size_t off_xp  = 65536;
    size_t xp_b    = (size_t)nrows * N_OUT_CH * 2;                  // Xp bf16: 12.8 MB
    size_t off_bs  = off_xp + ((xp_b + 7) & ~(size_t)7);                  // bstart
    size_t off_bc  = off_bs + (((size_t)(nb + 1) * 4 + 7) & ~(size_t)7);  // bcur
    size_t off_bh  = off_bc + (((size_t)nb * 4 + 7) & ~(size_t)7);        // bcnt
    size_t off_cv  = off_bh + (((size_t)nb * 4 + 7) & ~(size_t)7);        // colbuf
    size_t need    = off_cv + (size_t)nnz * 8;                      // 12.8 MB

    ushort* Wbf = (ushort*)((char*)d_ws + off_wbf);
    ushort* Xp  = (ushort*)((char*)d_ws + off_xp);

    wbf_kernel<<<(N_OUT_CH * N_IN_CH + 255) / 256, 256, 0, stream>>>(W, Wbf);
    mfma_gemm_kernel<<<(nrows + 63) / 64, 256, 0, stream>>>(X, Wbf, Xp, nrows);

    if (ws_size >= need && nb <= NBK) {
        int*  bstart = (int*)((char*)d_ws + off_bs);
        int*  bcur   = (int*)((char*)d_ws + off_bc);
        int*  bcnt   = (int*)((char*)d_ws + off_bh);
        int2* colbuf = (int2*)((char*)d_ws + off_cv);

        hipMemsetAsync(bcnt, 0, (size_t)nb * 4, stream);
        bhist_kernel<<<512, 256, 0, stream>>>(L_rows, bcnt, nnz, nb);
        bscan_kernel<<<1, 256, 0, stream>>>(bcnt, bstart, bcur, nb, nnz);
        bin_kernel<<<(nnz + B1_E - 1) / B1_E, 256, 0, stream>>>(L_rows, L_cols, L_vals,
                                                                bcur, colbuf, nnz, nb);
        bspmm_kernel<<<nb, 512, 0, stream>>>(bstart, colbuf, Xp, out, nrows);
    } else {
        hipMemsetAsync(d_out, 0, (size_t)out_size * sizeof(float), stream);
        long long total = (long long)nnz * 64;
        spmm_atomic_kernel<<<(int)((total + 255) / 256), 256, 0, stream>>>(
            L_rows, L_cols, L_vals, Xp, out, nnz);
    }
}

// Round 3
// 325.319 us; speedup vs baseline: 2.9294x; 2.9294x over previous
//
#include <hip/hip_runtime.h>

#define N_IN_CH 256
#define N_OUT_CH 64
#define XPAD 264    // 256 + 8 ushort pad: row stride 528 B -> conflict-free b128
#define BROW 128    // rows per bucket
#define NBK 1024    // max buckets: ceil(100000/128) = 782
#define B1_E 8192   // edges per bin_kernel block
#define EDGECAP 4096  // LDS edge buffer per bucket (mean 2048, 45-sigma bound)

typedef __attribute__((ext_vector_type(8))) short short8;
typedef __attribute__((ext_vector_type(4))) float f32x4;

__device__ inline ushort f2bf(float f) {
    unsigned u = __float_as_uint(f);
    return (ushort)((u + 0x7FFFu + ((u >> 16) & 1u)) >> 16);   // RTNE
}
__device__ inline float bf2f(ushort u) {
    return __uint_as_float(((unsigned)u) << 16);
}

// --- Kernel 1: W [64][256] fp32 -> bf16 ---
__global__ void wbf_kernel(const float* __restrict__ W, ushort* __restrict__ Wbf) {
    int i = blockIdx.x * blockDim.x + threadIdx.x;
    if (i < N_OUT_CH * N_IN_CH) Wbf[i] = f2bf(W[i]);
}

// --- Kernel 2: Xp = X @ W^T via bf16 MFMA; 64 rows/block, K=256 in one shot ---
__global__ __launch_bounds__(256) void mfma_gemm_kernel(const float* __restrict__ X,
        const ushort* __restrict__ Wbf, ushort* __restrict__ Xp, int nrows) {
    __shared__ ushort Xs[64 * XPAD];
    __shared__ ushort Ws[64 * XPAD];

    const int tid = threadIdx.x;
    const int row0 = blockIdx.x * 64;

    #pragma unroll
    for (int it = 0; it < 16; ++it) {
        int f = it * 256 + tid;
        int n = f >> 6, c4 = f & 63;
        ushort4 v = *(const ushort4*)&Wbf[n * N_IN_CH + c4 * 4];
        *(ushort4*)&Ws[n * XPAD + c4 * 4] = v;
    }
    #pragma unroll
    for (int it = 0; it < 16; ++it) {
        int f = it * 256 + tid;
        int r = f >> 6, c4 = f & 63;
        int gr = row0 + r;
        float4 x = make_float4(0.f, 0.f, 0.f, 0.f);
        if (gr < nrows) x = *(const float4*)&X[(size_t)gr * N_IN_CH + c4 * 4];
        ushort4 u;
        u.x = f2bf(x.x); u.y = f2bf(x.y); u.z = f2bf(x.z); u.w = f2bf(x.w);
        *(ushort4*)&Xs[r * XPAD + c4 * 4] = u;
    }
    __syncthreads();

    const int wave = tid >> 6, lane = tid & 63;
    const int ml = lane & 15, quad = lane >> 4;

    const ushort* abase = &Xs[(wave * 16 + ml) * XPAD + quad * 8];
    short8 a[8];
    #pragma unroll
    for (int kt = 0; kt < 8; ++kt) a[kt] = *(const short8*)&abase[kt * 32];

    const ushort* bbase = &Ws[ml * XPAD + quad * 8];

    #pragma unroll
    for (int nt = 0; nt < 4; ++nt) {
        f32x4 acc = {0.f, 0.f, 0.f, 0.f};
        #pragma unroll
        for (int kt = 0; kt < 8; ++kt) {
            short8 b = *(const short8*)&bbase[nt * 16 * XPAD + kt * 32];
            acc = __builtin_amdgcn_mfma_f32_16x16x32_bf16(a[kt], b, acc, 0, 0, 0);
        }
        #pragma unroll
        for (int reg = 0; reg < 4; ++reg) {
            int gr = row0 + wave * 16 + quad * 4 + reg;
            if (gr < nrows)
                Xp[(size_t)gr * N_OUT_CH + nt * 16 + ml] = f2bf(acc[reg]);
        }
    }
}

// --- Bucket histogram: nb bins (row >> 7), LDS-staged ---
__global__ __launch_bounds__(256) void bhist_kernel(const int* __restrict__ rows,
        int* __restrict__ bcnt, int nnz, int nb) {
    __shared__ int h[NBK];
    for (int i = threadIdx.x; i < nb; i += 256) h[i] = 0;
    __syncthreads();
    for (int e = blockIdx.x * 256 + threadIdx.x; e < nnz; e += gridDim.x * 256)
        atomicAdd(&h[rows[e] >> 7], 1);
    __syncthreads();
    for (int i = threadIdx.x; i < nb; i += 256) {
        int c = h[i];
        if (c) atomicAdd(&bcnt[i], c);
    }
}

// --- Bucket exclusive scan (single block, <=1024 buckets, 4/thread) ---
__global__ __launch_bounds__(256) void bscan_kernel(const int* __restrict__ bcnt,
        int* __restrict__ bstart, int* __restrict__ bcur, int nb, int nnz) {
    __shared__ int sh[256];
    int t = threadIdx.x;
    int c[4];
    #pragma unroll
    for (int j = 0; j < 4; ++j) {
        int i = t * 4 + j;
        c[j] = (i < nb) ? bcnt[i] : 0;
    }
    int s = c[0] + c[1] + c[2] + c[3];
    sh[t] = s;
    __syncthreads();
    #pragma unroll
    for (int d = 1; d < 256; d <<= 1) {
        int a = (t >= d) ? sh[t - d] : 0;
        __syncthreads();
        sh[t] += a;
        __syncthreads();
    }
    int base = sh[t] - s;   // exclusive over thread chunks
    #pragma unroll
    for (int j = 0; j < 4; ++j) {
        int i = t * 4 + j;
        if (i < nb) { bstart[i] = base; bcur[i] = base; }
        base += c[j];
    }
    if (t == 0) bstart[nb] = nnz;
}

// --- B1: bin-append. Per block: LDS count -> 1 atomic per bucket -> contiguous
//     per-(block,bucket) segment writes of (row_local<<17|col, val). ---
__global__ __launch_bounds__(256) void bin_kernel(const int* __restrict__ rows,
        const int* __restrict__ cols, const float* __restrict__ vals,
        int* __restrict__ bcur, int2* __restrict__ colbuf, int nnz, int nb) {
    __shared__ int cnt[NBK];
    __shared__ int base[NBK];
    const int t = threadIdx.x;
    const int e0 = blockIdx.x * B1_E;

    for (int i = t; i < nb; i += 256) cnt[i] = 0;
    __syncthreads();
    #pragma unroll
    for (int it = 0; it < B1_E / 256; ++it) {
        int e = e0 + it * 256 + t;
        if (e < nnz) atomicAdd(&cnt[rows[e] >> 7], 1);
    }
    __syncthreads();
    for (int i = t; i < nb; i += 256) {
        int c = cnt[i];
        base[i] = c ? atomicAdd(&bcur[i], c) : 0;
        cnt[i] = 0;
    }
    __syncthreads();
    #pragma unroll
    for (int it = 0; it < B1_E / 256; ++it) {
        int e = e0 + it * 256 + t;
        if (e < nnz) {
            int r = rows[e];
            int b = r >> 7;
            int pos = base[b] + atomicAdd(&cnt[b], 1);
            int2 cv;
            cv.x = cols[e] | ((r & 127) << 17);   // col < 2^17, row_local 7 bits
            cv.y = __float_as_int(vals[e]);
            colbuf[pos] = cv;
        }
    }
}

// --- Fused bucket sort + SpMM: one block per bucket. Sort bucket's edges into
//     a 32 KB LDS buffer (int LDS atomics only — float LDS atomics are a CAS
//     loop, 10x slower, measured R2), then each wave consumes whole rows with
//     register accumulation. Kills the colval global round-trip. ---
__global__ __launch_bounds__(512) void bspmm_kernel(const int* __restrict__ bstart,
        const int2* __restrict__ colbuf, const ushort* __restrict__ Xp,
        float* __restrict__ out, int nrows) {
    __shared__ int2 ebuf[EDGECAP];       // 32 KB
    __shared__ int rc[BROW];
    __shared__ int rb[BROW + 1];
    const int b = blockIdx.x, t = threadIdx.x;
    const int bs = bstart[b], be = bstart[b + 1];
    const int ne = be - bs;
    const int row0 = b * BROW;
    const int wave = t >> 6, lane = t & 63;

    if (ne <= EDGECAP) {
        if (t < BROW) rc[t] = 0;
        __syncthreads();
        for (int i = bs + t; i < be; i += 512)
            atomicAdd(&rc[(colbuf[i].x >> 17) & (BROW - 1)], 1);
        __syncthreads();
        int c0 = (t < BROW) ? rc[t] : 0;
        // inclusive Hillis-Steele scan over BROW entries
        #pragma unroll
        for (int d = 1; d < BROW; d <<= 1) {
            int a = (t < BROW && t >= d) ? rc[t - d] : 0;
            __syncthreads();
            if (t < BROW) rc[t] += a;
            __syncthreads();
        }
        if (t < BROW) { rb[t] = rc[t] - c0; }
        if (t == 0) rb[BROW] = ne;
        __syncthreads();
        if (t < BROW) rc[t] = 0;
        __syncthreads();
        for (int i = bs + t; i < be; i += 512) {
            int2 cv = colbuf[i];
            int rl = (cv.x >> 17) & (BROW - 1);
            int pos = rb[rl] + atomicAdd(&rc[rl], 1);
            ebuf[pos] = cv;
        }
        __syncthreads();
        // consume: wave w owns rows w, w+8, ...; lane = channel
        for (int r = wave; r < BROW; r += 8) {
            int gr = row0 + r;
            if (gr >= nrows) break;
            int s = rb[r], e = rb[r + 1];
            float a0 = 0.f, a1 = 0.f, a2 = 0.f, a3 = 0.f;
            int i = s;
            for (; i + 4 <= e; i += 4) {
                int2 c0v = ebuf[i], c1v = ebuf[i + 1];
                int2 c2v = ebuf[i + 2], c3v = ebuf[i + 3];
                float x0 = bf2f(Xp[(size_t)(c0v.x & 0x1FFFF) * N_OUT_CH + lane]);
                float x1 = bf2f(Xp[(size_t)(c1v.x & 0x1FFFF) * N_OUT_CH + lane]);
                float x2 = bf2f(Xp[(size_t)(c2v.x & 0x1FFFF) * N_OUT_CH + lane]);
                float x3 = bf2f(Xp[(size_t)(c3v.x & 0x1FFFF) * N_OUT_CH + lane]);
                a0 += __int_as_float(c0v.y) * x0;
                a1 += __int_as_float(c1v.y) * x1;
                a2 += __int_as_float(c2v.y) * x2;
                a3 += __int_as_float(c3v.y) * x3;
            }
            for (; i < e; ++i) {
                int2 cv = ebuf[i];
                a0 += __int_as_float(cv.y) *
                      bf2f(Xp[(size_t)(cv.x & 0x1FFFF) * N_OUT_CH + lane]);
            }
            out[(size_t)gr * N_OUT_CH + lane] = (a0 + a1) + (a2 + a3);
        }
    } else {
        // Oversized bucket (not reachable for uniform-random rows): each wave
        // filters the whole bucket per owned row. Correct, never fast-path.
        for (int r = wave; r < BROW; r += 8) {
            int gr = row0 + r;
            if (gr >= nrows) break;
            float a = 0.f;
            for (int i = bs; i < be; ++i) {
                int2 cv = colbuf[i];
                if (((cv.x >> 17) & (BROW - 1)) == r)
                    a += __int_as_float(cv.y) *
                         bf2f(Xp[(size_t)(cv.x & 0x1FFFF) * N_OUT_CH + lane]);
            }
            out[(size_t)gr * N_OUT_CH + lane] = a;
        }
    }
}

// --- Fallback atomic SpMM (ws too small — not expected) ---
__global__ __launch_bounds__(256) void spmm_atomic_kernel(const int* __restrict__ rows,
        const int* __restrict__ cols, const float* __restrict__ vals,
        const ushort* __restrict__ Xp, float* __restrict__ out, int nnz) {
    int t = blockIdx.x * blockDim.x + threadIdx.x;
    int e = t >> 6;
    int c = t & 63;
    if (e < nnz) {
        atomicAdd(&out[(size_t)rows[e] * N_OUT_CH + c],
                  vals[e] * bf2f(Xp[(size_t)cols[e] * N_OUT_CH + c]));
    }
}

extern "C" void kernel_launch(void* const* d_in, const int* in_sizes, int n_in,
                              void* d_out, int out_size, void* d_ws, size_t ws_size,
                              hipStream_t stream) {
    const float* X      = (const float*)d_in[2];
    const float* W      = (const float*)d_in[3];
    const int*   L_rows = (const int*)d_in[4];
    const int*   L_cols = (const int*)d_in[5];
    const float* L_vals = (const float*)d_in[6];
    float* out = (float*)d_out;

    const int nrows = in_sizes[2] / N_IN_CH;   // 100000
    const int nnz   = in_sizes[4];             // 1600000
    const int nb    = (nrows + BROW - 1) / BROW;   // 782 buckets

    // workspace layout (8B-aligned)
    size_t off_wbf = 0;                                             // 32 KB
    size_t off_xp  = 65536;
    size_t xp_b    = (size_t)nrows * N_OUT_CH * 2;                  // Xp bf16: 12.8 MB
    size_t off_bs  = off_xp + ((xp_b + 7) & ~(size_t)7);                  // bstart
    size_t off_bc  = off_bs + (((size_t)(nb + 1) * 4 + 7) & ~(size_t)7);  // bcur
    size_t off_bh  = off_bc + (((size_t)nb * 4 + 7) & ~(size_t)7);        // bcnt
    size_t off_cv  = off_bh + (((size_t)nb * 4 + 7) & ~(size_t)7);        // colbuf
    size_t need    = off_cv + (size_t)nnz * 8;                      // 12.8 MB

    ushort* Wbf = (ushort*)((char*)d_ws + off_wbf);
    ushort* Xp  = (ushort*)((char*)d_ws + off_xp);

    wbf_kernel<<<(N_OUT_CH * N_IN_CH + 255) / 256, 256, 0, stream>>>(W, Wbf);
    mfma_gemm_kernel<<<(nrows + 63) / 64, 256, 0, stream>>>(X, Wbf, Xp, nrows);

    if (ws_size >= need && nb <= NBK) {
        int*  bstart = (int*)((char*)d_ws + off_bs);
        int*  bcur   = (int*)((char*)d_ws + off_bc);
        int*  bcnt   = (int*)((char*)d_ws + off_bh);
        int2* colbuf = (int2*)((char*)d_ws + off_cv);

        hipMemsetAsync(bcnt, 0, (size_t)nb * 4, stream);
        bhist_kernel<<<512, 256, 0, stream>>>(L_rows, bcnt, nnz, nb);
        bscan_kernel<<<1, 256, 0, stream>>>(bcnt, bstart, bcur, nb, nnz);
        bin_kernel<<<(nnz + B1_E - 1) / B1_E, 256, 0, stream>>>(L_rows, L_cols, L_vals,
                                                                bcur, colbuf, nnz, nb);
        bspmm_kernel<<<nb, 512, 0, stream>>>(bstart, colbuf, Xp, out, nrows);
    } else {
        hipMemsetAsync(d_out, 0, (size_t)out_size * sizeof(float), stream);
        long long total = (long long)nnz * 64;
        spmm_atomic_kernel<<<(int)((total + 255) / 256), 256, 0, stream>>>(
            L_rows, L_cols, L_vals, Xp, out, nnz);
    }
}

// Round 4
// 309.634 us; speedup vs baseline: 3.0778x; 1.0507x over previous
//
#include <hip/hip_runtime.h>

#define N_IN_CH 256
#define N_OUT_CH 64
#define BROW 128      // rows per bucket
#define NBK 1024      // max buckets: ceil(100000/128) = 782
#define B1_E 8192     // edges per bin_kernel block
#define ECAP 4096     // edges per padded bucket region AND LDS buffer (mean 2048, 45-sigma)
#define OVFCAP 65536  // overflow edge capacity (never hit for uniform rows)

typedef __attribute__((ext_vector_type(8))) short short8;
typedef __attribute__((ext_vector_type(4))) float f32x4;

__device__ inline ushort f2bf(float f) {
    unsigned u = __float_as_uint(f);
    return (ushort)((u + 0x7FFFu + ((u >> 16) & 1u)) >> 16);   // RTNE
}
__device__ inline float bf2f(ushort u) {
    return __uint_as_float(((unsigned)u) << 16);
}

// --- Kernel 1: W [64][256] fp32 -> bf16 ---
__global__ void wbf_kernel(const float* __restrict__ W, ushort* __restrict__ Wbf) {
    int i = blockIdx.x * blockDim.x + threadIdx.x;
    if (i < N_OUT_CH * N_IN_CH) Wbf[i] = f2bf(W[i]);
}

// --- Kernel 2: Xp = X @ W^T, LDS-free MFMA GEMM.
//     A-frags loaded straight from global X (fully-used 64B lines: 16 rows x
//     128B per kt across the wave), B-frags from L1-resident 32KB Wbf.
//     R3 post-mortem: 66KB LDS staging capped occupancy at 2 blocks/CU (17.7%)
//     and cost 1M bank-conflict cycles; this version has zero LDS, zero
//     barriers. ---
__global__ __launch_bounds__(256) void mfma_gemm_kernel(const float* __restrict__ X,
        const ushort* __restrict__ Wbf, ushort* __restrict__ Xp, int nrows) {
    const int tid = threadIdx.x;
    const int wave = tid >> 6, lane = tid & 63;
    const int ml = lane & 15, q = lane >> 4;
    const int rowbase = blockIdx.x * 64 + wave * 16;
    const int gr_a = rowbase + ml;

    // A-fragments: lane (ml,q) holds A[m=ml][k=kt*32+q*8 .. +8)
    short8 a[8];
    if (gr_a < nrows) {
        const float* xrow = X + (size_t)gr_a * N_IN_CH + q * 8;
        #pragma unroll
        for (int kt = 0; kt < 8; ++kt) {
            float4 f0 = *(const float4*)&xrow[kt * 32];
            float4 f1 = *(const float4*)&xrow[kt * 32 + 4];
            short8 s;
            s[0] = (short)f2bf(f0.x); s[1] = (short)f2bf(f0.y);
            s[2] = (short)f2bf(f0.z); s[3] = (short)f2bf(f0.w);
            s[4] = (short)f2bf(f1.x); s[5] = (short)f2bf(f1.y);
            s[6] = (short)f2bf(f1.z); s[7] = (short)f2bf(f1.w);
            a[kt] = s;
        }
    } else {
        #pragma unroll
        for (int kt = 0; kt < 8; ++kt) a[kt] = (short8)0;
    }

    // B-fragments: lane (ml,q) holds B[k][n=nt*16+ml] = W[n][k], same k pattern
    const ushort* wb = Wbf + (size_t)ml * N_IN_CH + q * 8;

    #pragma unroll
    for (int nt = 0; nt < 4; ++nt) {
        f32x4 acc = {0.f, 0.f, 0.f, 0.f};
        #pragma unroll
        for (int kt = 0; kt < 8; ++kt) {
            short8 b = *(const short8*)&wb[nt * 16 * N_IN_CH + kt * 32];
            acc = __builtin_amdgcn_mfma_f32_16x16x32_bf16(a[kt], b, acc, 0, 0, 0);
        }
        // C/D: col = lane&15 (n within tile), row = q*4+reg (m within tile)
        #pragma unroll
        for (int reg = 0; reg < 4; ++reg) {
            int gr = rowbase + q * 4 + reg;
            if (gr < nrows)
                Xp[(size_t)gr * N_OUT_CH + nt * 16 + ml] = f2bf(acc[reg]);
        }
    }
}

// --- B1: single-pass bin-append into PADDED bucket regions (b*ECAP).
//     Per block: LDS count -> 1 global atomic per bucket -> contiguous
//     per-(block,bucket) segment writes. No bhist/bscan pre-pass needed.
//     Edges that overflow a region (>=45-sigma, unreachable for uniform rows)
//     go to the overflow list, fixed up after bspmm. ---
__global__ __launch_bounds__(256) void bin_kernel(const int* __restrict__ rows,
        const int* __restrict__ cols, const float* __restrict__ vals,
        int* __restrict__ bcur, int* __restrict__ ovfcnt, int4* __restrict__ ovf,
        int2* __restrict__ colbuf, int nnz, int nb) {
    __shared__ int cnt[NBK];
    __shared__ int base[NBK];
    const int t = threadIdx.x;
    const int e0 = blockIdx.x * B1_E;

    for (int i = t; i < nb; i += 256) cnt[i] = 0;
    __syncthreads();
    #pragma unroll
    for (int it = 0; it < B1_E / 256; ++it) {
        int e = e0 + it * 256 + t;
        if (e < nnz) atomicAdd(&cnt[rows[e] >> 7], 1);
    }
    __syncthreads();
    for (int i = t; i < nb; i += 256) {
        int c = cnt[i];
        base[i] = c ? atomicAdd(&bcur[i], c) : 0;
        cnt[i] = 0;
    }
    __syncthreads();
    #pragma unroll
    for (int it = 0; it < B1_E / 256; ++it) {
        int e = e0 + it * 256 + t;
        if (e < nnz) {
            int r = rows[e];
            int b = r >> 7;
            int pib = base[b] + atomicAdd(&cnt[b], 1);
            if (pib < ECAP) {
                int2 cv;
                cv.x = cols[e] | ((r & 127) << 17);   // col < 2^17, row_local 7b
                cv.y = __float_as_int(vals[e]);
                colbuf[(size_t)b * ECAP + pib] = cv;
            } else {
                int op = atomicAdd(ovfcnt, 1);
                if (op < OVFCAP) {
                    int4 o; o.x = r; o.y = cols[e];
                    o.z = __float_as_int(vals[e]); o.w = 0;
                    ovf[op] = o;
                }
            }
        }
    }
}

// --- Fused bucket sort + SpMM: one block per bucket. Sort bucket's edges into
//     a 32 KB LDS buffer (int LDS atomics only — float LDS atomics are a CAS
//     loop, 10x slower, measured R2), then each wave consumes whole rows with
//     register accumulation. ---
__global__ __launch_bounds__(512) void bspmm_kernel(const int* __restrict__ bcur,
        const int2* __restrict__ colbuf, const ushort* __restrict__ Xp,
        float* __restrict__ out, int nrows) {
    __shared__ int2 ebuf[ECAP];       // 32 KB
    __shared__ int rc[BROW];
    __shared__ int rb[BROW + 1];
    const int b = blockIdx.x, t = threadIdx.x;
    const int ne = min(bcur[b], ECAP);
    const int2* cb = colbuf + (size_t)b * ECAP;
    const int row0 = b * BROW;
    const int wave = t >> 6, lane = t & 63;

    if (t < BROW) rc[t] = 0;
    __syncthreads();
    for (int i = t; i < ne; i += 512)
        atomicAdd(&rc[(cb[i].x >> 17) & (BROW - 1)], 1);
    __syncthreads();
    int c0 = (t < BROW) ? rc[t] : 0;
    // inclusive Hillis-Steele scan over BROW entries
    #pragma unroll
    for (int d = 1; d < BROW; d <<= 1) {
        int a = (t < BROW && t >= d) ? rc[t - d] : 0;
        __syncthreads();
        if (t < BROW) rc[t] += a;
        __syncthreads();
    }
    if (t < BROW) rb[t] = rc[t] - c0;
    if (t == 0) rb[BROW] = ne;
    __syncthreads();
    if (t < BROW) rc[t] = 0;
    __syncthreads();
    for (int i = t; i < ne; i += 512) {
        int2 cv = cb[i];
        int rl = (cv.x >> 17) & (BROW - 1);
        int pos = rb[rl] + atomicAdd(&rc[rl], 1);
        ebuf[pos] = cv;
    }
    __syncthreads();
    // consume: wave w owns rows w, w+8, ...; lane = channel
    for (int r = wave; r < BROW; r += 8) {
        int gr = row0 + r;
        if (gr >= nrows) break;
        int s = rb[r], e = rb[r + 1];
        float a0 = 0.f, a1 = 0.f, a2 = 0.f, a3 = 0.f;
        int i = s;
        for (; i + 4 <= e; i += 4) {
            int2 c0v = ebuf[i], c1v = ebuf[i + 1];
            int2 c2v = ebuf[i + 2], c3v = ebuf[i + 3];
            float x0 = bf2f(Xp[(size_t)(c0v.x & 0x1FFFF) * N_OUT_CH + lane]);
            float x1 = bf2f(Xp[(size_t)(c1v.x & 0x1FFFF) * N_OUT_CH + lane]);
            float x2 = bf2f(Xp[(size_t)(c2v.x & 0x1FFFF) * N_OUT_CH + lane]);
            float x3 = bf2f(Xp[(size_t)(c3v.x & 0x1FFFF) * N_OUT_CH + lane]);
            a0 += __int_as_float(c0v.y) * x0;
            a1 += __int_as_float(c1v.y) * x1;
            a2 += __int_as_float(c2v.y) * x2;
            a3 += __int_as_float(c3v.y) * x3;
        }
        for (; i < e; ++i) {
            int2 cv = ebuf[i];
            a0 += __int_as_float(cv.y) *
                  bf2f(Xp[(size_t)(cv.x & 0x1FFFF) * N_OUT_CH + lane]);
        }
        out[(size_t)gr * N_OUT_CH + lane] = (a0 + a1) + (a2 + a3);
    }
}

// --- Overflow fix-up: atomically add any edges that overflowed a bucket
//     region (normally zero; returns immediately). Runs after bspmm. ---
__global__ __launch_bounds__(256) void ovf_kernel(const int* __restrict__ ovfcnt,
        const int4* __restrict__ ovf, const ushort* __restrict__ Xp,
        float* __restrict__ out) {
    int n = min(ovfcnt[0], OVFCAP);
    int lane = threadIdx.x & 63;
    for (int e = blockIdx.x * 4 + (threadIdx.x >> 6); e < n; e += gridDim.x * 4) {
        int4 v = ovf[e];
        atomicAdd(&out[(size_t)v.x * N_OUT_CH + lane],
                  __int_as_float(v.z) * bf2f(Xp[(size_t)v.y * N_OUT_CH + lane]));
    }
}

// --- Fallback atomic SpMM (ws too small — not expected) ---
__global__ __launch_bounds__(256) void spmm_atomic_kernel(const int* __restrict__ rows,
        const int* __restrict__ cols, const float* __restrict__ vals,
        const ushort* __restrict__ Xp, float* __restrict__ out, int nnz) {
    int t = blockIdx.x * blockDim.x + threadIdx.x;
    int e = t >> 6;
    int c = t & 63;
    if (e < nnz) {
        atomicAdd(&out[(size_t)rows[e] * N_OUT_CH + c],
                  vals[e] * bf2f(Xp[(size_t)cols[e] * N_OUT_CH + c]));
    }
}

extern "C" void kernel_launch(void* const* d_in, const int* in_sizes, int n_in,
                              void* d_out, int out_size, void* d_ws, size_t ws_size,
                              hipStream_t stream) {
    const float* X      = (const float*)d_in[2];
    const float* W      = (const float*)d_in[3];
    const int*   L_rows = (const int*)d_in[4];
    const int*   L_cols = (const int*)d_in[5];
    const float* L_vals = (const float*)d_in[6];
    float* out = (float*)d_out;

    const int nrows = in_sizes[2] / N_IN_CH;   // 100000
    const int nnz   = in_sizes[4];             // 1600000
    const int nb    = (nrows + BROW - 1) / BROW;   // 782 buckets

    // workspace layout (16B-aligned blocks)
    size_t off_wbf = 0;                                              // 32 KB
    size_t off_xp  = 65536;
    size_t xp_b    = (size_t)nrows * N_OUT_CH * 2;                   // Xp bf16: 12.8 MB
    size_t off_bc  = off_xp + ((xp_b + 15) & ~(size_t)15);           // bcur[nb] + ovfcnt
    size_t off_ov  = off_bc + (((size_t)(nb + 1) * 4 + 15) & ~(size_t)15);  // ovf int4
    size_t off_cv  = off_ov + (size_t)OVFCAP * 16;                   // colbuf padded
    size_t need    = off_cv + (size_t)nb * ECAP * 8;                 // 25.6 MB

    ushort* Wbf = (ushort*)((char*)d_ws + off_wbf);
    ushort* Xp  = (ushort*)((char*)d_ws + off_xp);

    wbf_kernel<<<(N_OUT_CH * N_IN_CH + 255) / 256, 256, 0, stream>>>(W, Wbf);
    mfma_gemm_kernel<<<(nrows + 63) / 64, 256, 0, stream>>>(X, Wbf, Xp, nrows);

    if (ws_size >= need && nb <= NBK) {
        int*  bcur   = (int*)((char*)d_ws + off_bc);      // [nb] cursors
        int*  ovfcnt = bcur + nb;                          // 1 int
        int4* ovf    = (int4*)((char*)d_ws + off_ov);
        int2* colbuf = (int2*)((char*)d_ws + off_cv);

        hipMemsetAsync(bcur, 0, (size_t)(nb + 1) * 4, stream);
        bin_kernel<<<(nnz + B1_E - 1) / B1_E, 256, 0, stream>>>(L_rows, L_cols, L_vals,
                bcur, ovfcnt, ovf, colbuf, nnz, nb);
        bspmm_kernel<<<nb, 512, 0, stream>>>(bcur, colbuf, Xp, out, nrows);
        ovf_kernel<<<16, 256, 0, stream>>>(ovfcnt, ovf, Xp, out);
    } else {
        hipMemsetAsync(d_out, 0, (size_t)out_size * sizeof(float), stream);
        long long total = (long long)nnz * 64;
        spmm_atomic_kernel<<<(int)((total + 255) / 256), 256, 0, stream>>>(
            L_rows, L_cols, L_vals, Xp, out, nnz);
    }
}

// Round 6
// 257.074 us; speedup vs baseline: 3.7071x; 1.2045x over previous
//
#include <hip/hip_runtime.h>

#define N_IN_CH 256
#define N_OUT_CH 64
#define XPAD 264      // 256 + 8 ushort pad: b128 LDS reads spread evenly over banks
#define BROW 128      // rows per bucket
#define NBK 1024      // max buckets: ceil(100000/128) = 782
#define B1_E 4096     // edges per bin_kernel block (1024 thr x 4 edges)
#define ECAP 4096     // edges per padded bucket region AND LDS buffer (mean 2048, 45-sigma)
#define OVFCAP 65536  // overflow edge capacity (never hit for uniform rows)
#define GEMM_GRID 768 // persistent GEMM blocks: 3/CU (VGPR-capped 12 waves/CU)

typedef __attribute__((ext_vector_type(8))) short short8;
typedef __attribute__((ext_vector_type(4))) float f32x4;

__device__ inline ushort f2bf(float f) {
    unsigned u = __float_as_uint(f);
    return (ushort)((u + 0x7FFFu + ((u >> 16) & 1u)) >> 16);   // RTNE
}
__device__ inline float bf2f(ushort u) {
    return __uint_as_float(((unsigned)u) << 16);
}

// --- Kernel 1: W [64][256] fp32 -> bf16 ---
__global__ void wbf_kernel(const float* __restrict__ W, ushort* __restrict__ Wbf) {
    int i = blockIdx.x * blockDim.x + threadIdx.x;
    if (i < N_OUT_CH * N_IN_CH) Wbf[i] = f2bf(W[i]);
}

// --- Kernel 2: persistent pipelined MFMA GEMM.
//     R4 post-mortem: one-tile-per-block was latency-serialized (VALUBusy 4.7%)
//     and global B-loads shared vmcnt with A-loads, draining the prefetch.
//     Now: W staged once per block into LDS (B-reads on lgkmcnt, decoupled),
//     each wave grid-strides over 16-row tiles with A-prefetch double-buffer:
//     convert raw(t), issue raw(t+1) global loads, compute t from regs+LDS. ---
__global__ __launch_bounds__(256) void mfma_gemm_kernel(const float* __restrict__ X,
        const ushort* __restrict__ Wbf, ushort* __restrict__ Xp, int nrows) {
    __shared__ ushort Ws[64 * XPAD];   // 33.8 KB
    const int tid = threadIdx.x;

    #pragma unroll
    for (int it = 0; it < 16; ++it) {
        int f = it * 256 + tid;
        int n = f >> 6, c4 = f & 63;
        *(ushort4*)&Ws[n * XPAD + c4 * 4] = *(const ushort4*)&Wbf[n * N_IN_CH + c4 * 4];
    }
    __syncthreads();

    const int wave = tid >> 6, lane = tid & 63;
    const int ml = lane & 15, q = lane >> 4;
    const int ntiles = (nrows + 15) >> 4;
    const int nw = gridDim.x * 4;
    int t = blockIdx.x * 4 + wave;

    const ushort* wsb = &Ws[ml * XPAD + q * 8];

    float4 raw[16];

#define ISSUE_TILE(tt)                                                     \
    do {                                                                   \
        int gr_ = (tt) * 16 + ml;                                          \
        if (gr_ < nrows) {                                                 \
            const float* xr_ = X + (size_t)gr_ * N_IN_CH + q * 8;          \
            _Pragma("unroll")                                              \
            for (int kt_ = 0; kt_ < 8; ++kt_) {                            \
                raw[2 * kt_]     = *(const float4*)&xr_[kt_ * 32];         \
                raw[2 * kt_ + 1] = *(const float4*)&xr_[kt_ * 32 + 4];     \
            }                                                              \
        } else {                                                           \
            _Pragma("unroll")                                              \
            for (int i_ = 0; i_ < 16; ++i_)                                \
                raw[i_] = make_float4(0.f, 0.f, 0.f, 0.f);                 \
        }                                                                  \
    } while (0)

    if (t < ntiles) ISSUE_TILE(t);

    while (t < ntiles) {
        // convert current tile raw -> bf16 fragments (frees raw for prefetch)
        short8 a[8];
        #pragma unroll
        for (int kt = 0; kt < 8; ++kt) {
            float4 f0 = raw[2 * kt], f1 = raw[2 * kt + 1];
            short8 s;
            s[0] = (short)f2bf(f0.x); s[1] = (short)f2bf(f0.y);
            s[2] = (short)f2bf(f0.z); s[3] = (short)f2bf(f0.w);
            s[4] = (short)f2bf(f1.x); s[5] = (short)f2bf(f1.y);
            s[6] = (short)f2bf(f1.z); s[7] = (short)f2bf(f1.w);
            a[kt] = s;
        }
        int tn = t + nw;
        if (tn < ntiles) ISSUE_TILE(tn);   // in flight across the whole compute

        #pragma unroll
        for (int nt = 0; nt < 4; ++nt) {
            f32x4 acc = {0.f, 0.f, 0.f, 0.f};
            #pragma unroll
            for (int kt = 0; kt < 8; ++kt) {
                short8 b = *(const short8*)&wsb[nt * 16 * XPAD + kt * 32];
                acc = __builtin_amdgcn_mfma_f32_16x16x32_bf16(a[kt], b, acc, 0, 0, 0);
            }
            // C/D: col = lane&15 (n within tile), row = q*4+reg (m within tile)
            #pragma unroll
            for (int reg = 0; reg < 4; ++reg) {
                int gr = t * 16 + q * 4 + reg;
                if (gr < nrows)
                    Xp[(size_t)gr * N_OUT_CH + nt * 16 + ml] = f2bf(acc[reg]);
            }
        }
        t = tn;
    }
#undef ISSUE_TILE
}

// --- B1: single-pass bin-append into PADDED bucket regions (b*ECAP).
//     1024 threads x 4 edges (int4/float4 loads) per block: 391 blocks,
//     ~2 blocks/CU (R4: 196 blocks at 7% occupancy was latency-starved).
//     LDS count -> 1 global atomic per bucket -> contiguous segment writes.
//     Overflowing edges (>=45-sigma, unreachable for uniform rows) go to the
//     overflow list, fixed up after bspmm. ---
__global__ __launch_bounds__(1024) void bin_kernel(const int* __restrict__ rows,
        const int* __restrict__ cols, const float* __restrict__ vals,
        int* __restrict__ bcur, int* __restrict__ ovfcnt, int4* __restrict__ ovf,
        int2* __restrict__ colbuf, int nnz, int nb) {
    __shared__ int cnt[NBK];
    __shared__ int base[NBK];
    const int t = threadIdx.x;

    for (int i = t; i < nb; i += 1024) cnt[i] = 0;
    __syncthreads();

    const int e = blockIdx.x * B1_E + t * 4;
    int nval = nnz - e;
    if (nval > 4) nval = 4;
    if (nval < 0) nval = 0;

    int r[4], c[4]; float v[4];
    if (nval == 4) {
        int4 rr = *(const int4*)&rows[e];
        int4 cc = *(const int4*)&cols[e];
        float4 vv = *(const float4*)&vals[e];
        r[0] = rr.x; r[1] = rr.y; r[2] = rr.z; r[3] = rr.w;
        c[0] = cc.x; c[1] = cc.y; c[2] = cc.z; c[3] = cc.w;
        v[0] = vv.x; v[1] = vv.y; v[2] = vv.z; v[3] = vv.w;
    } else {
        #pragma unroll
        for (int j = 0; j < 4; ++j)
            if (j < nval) { r[j] = rows[e + j]; c[j] = cols[e + j]; v[j] = vals[e + j]; }
    }

    #pragma unroll
    for (int j = 0; j < 4; ++j)
        if (j < nval) atomicAdd(&cnt[r[j] >> 7], 1);
    __syncthreads();

    for (int i = t; i < nb; i += 1024) {
        int cn = cnt[i];
        base[i] = cn ? atomicAdd(&bcur[i], cn) : 0;
        cnt[i] = 0;
    }
    __syncthreads();

    #pragma unroll
    for (int j = 0; j < 4; ++j) {
        if (j < nval) {
            int b = r[j] >> 7;
            int pib = base[b] + atomicAdd(&cnt[b], 1);
            if (pib < ECAP) {
                int2 cv;
                cv.x = c[j] | ((r[j] & 127) << 17);   // col < 2^17, row_local 7b
                cv.y = __float_as_int(v[j]);
                colbuf[(size_t)b * ECAP + pib] = cv;
            } else {
                int op = atomicAdd(ovfcnt, 1);
                if (op < OVFCAP) {
                    int4 o; o.x = r[j]; o.y = c[j];
                    o.z = __float_as_int(v[j]); o.w = 0;
                    ovf[op] = o;
                }
            }
        }
    }
}

// --- Fused bucket sort + SpMM: one block per bucket. Sort bucket's edges into
//     a 32 KB LDS buffer (int LDS atomics only — float LDS atomics are a CAS
//     loop, 10x slower, measured R2), then each wave consumes whole rows with
//     register accumulation. ---
__global__ __launch_bounds__(512) void bspmm_kernel(const int* __restrict__ bcur,
        const int2* __restrict__ colbuf, const ushort* __restrict__ Xp,
        float* __restrict__ out, int nrows) {
    __shared__ int2 ebuf[ECAP];       // 32 KB
    __shared__ int rc[BROW];
    __shared__ int rb[BROW + 1];
    const int b = blockIdx.x, t = threadIdx.x;
    const int ne = min(bcur[b], ECAP);
    const int2* cb = colbuf + (size_t)b * ECAP;
    const int row0 = b * BROW;
    const int wave = t >> 6, lane = t & 63;

    if (t < BROW) rc[t] = 0;
    __syncthreads();
    for (int i = t; i < ne; i += 512)
        atomicAdd(&rc[(cb[i].x >> 17) & (BROW - 1)], 1);
    __syncthreads();
    int c0 = (t < BROW) ? rc[t] : 0;
    // inclusive Hillis-Steele scan over BROW entries
    #pragma unroll
    for (int d = 1; d < BROW; d <<= 1) {
        int a = (t < BROW && t >= d) ? rc[t - d] : 0;
        __syncthreads();
        if (t < BROW) rc[t] += a;
        __syncthreads();
    }
    if (t < BROW) rb[t] = rc[t] - c0;
    if (t == 0) rb[BROW] = ne;
    __syncthreads();
    if (t < BROW) rc[t] = 0;
    __syncthreads();
    for (int i = t; i < ne; i += 512) {
        int2 cv = cb[i];
        int rl = (cv.x >> 17) & (BROW - 1);
        int pos = rb[rl] + atomicAdd(&rc[rl], 1);
        ebuf[pos] = cv;
    }
    __syncthreads();
    // consume: wave w owns rows w, w+8, ...; lane = channel
    for (int r = wave; r < BROW; r += 8) {
        int gr = row0 + r;
        if (gr >= nrows) break;
        int s = rb[r], e = rb[r + 1];
        float a0 = 0.f, a1 = 0.f, a2 = 0.f, a3 = 0.f;
        int i = s;
        for (; i + 4 <= e; i += 4) {
            int2 c0v = ebuf[i], c1v = ebuf[i + 1];
            int2 c2v = ebuf[i + 2], c3v = ebuf[i + 3];
            float x0 = bf2f(Xp[(size_t)(c0v.x & 0x1FFFF) * N_OUT_CH + lane]);
            float x1 = bf2f(Xp[(size_t)(c1v.x & 0x1FFFF) * N_OUT_CH + lane]);
            float x2 = bf2f(Xp[(size_t)(c2v.x & 0x1FFFF) * N_OUT_CH + lane]);
            float x3 = bf2f(Xp[(size_t)(c3v.x & 0x1FFFF) * N_OUT_CH + lane]);
            a0 += __int_as_float(c0v.y) * x0;
            a1 += __int_as_float(c1v.y) * x1;
            a2 += __int_as_float(c2v.y) * x2;
            a3 += __int_as_float(c3v.y) * x3;
        }
        for (; i < e; ++i) {
            int2 cv = ebuf[i];
            a0 += __int_as_float(cv.y) *
                  bf2f(Xp[(size_t)(cv.x & 0x1FFFF) * N_OUT_CH + lane]);
        }
        out[(size_t)gr * N_OUT_CH + lane] = (a0 + a1) + (a2 + a3);
    }
}

// --- Overflow fix-up: atomically add any edges that overflowed a bucket
//     region (normally zero; returns immediately). Runs after bspmm. ---
__global__ __launch_bounds__(256) void ovf_kernel(const int* __restrict__ ovfcnt,
        const int4* __restrict__ ovf, const ushort* __restrict__ Xp,
        float* __restrict__ out) {
    int n = min(ovfcnt[0], OVFCAP);
    int lane = threadIdx.x & 63;
    for (int e = blockIdx.x * 4 + (threadIdx.x >> 6); e < n; e += gridDim.x * 4) {
        int4 v = ovf[e];
        atomicAdd(&out[(size_t)v.x * N_OUT_CH + lane],
                  __int_as_float(v.z) * bf2f(Xp[(size_t)v.y * N_OUT_CH + lane]));
    }
}

// --- Fallback atomic SpMM (ws too small — not expected) ---
__global__ __launch_bounds__(256) void spmm_atomic_kernel(const int* __restrict__ rows,
        const int* __restrict__ cols, const float* __restrict__ vals,
        const ushort* __restrict__ Xp, float* __restrict__ out, int nnz) {
    int t = blockIdx.x * blockDim.x + threadIdx.x;
    int e = t >> 6;
    int c = t & 63;
    if (e < nnz) {
        atomicAdd(&out[(size_t)rows[e] * N_OUT_CH + c],
                  vals[e] * bf2f(Xp[(size_t)cols[e] * N_OUT_CH + c]));
    }
}

extern "C" void kernel_launch(void* const* d_in, const int* in_sizes, int n_in,
                              void* d_out, int out_size, void* d_ws, size_t ws_size,
                              hipStream_t stream) {
    const float* X      = (const float*)d_in[2];
    const float* W      = (const float*)d_in[3];
    const int*   L_rows = (const int*)d_in[4];
    const int*   L_cols = (const int*)d_in[5];
    const float* L_vals = (const float*)d_in[6];
    float* out = (float*)d_out;

    const int nrows = in_sizes[2] / N_IN_CH;   // 100000
    const int nnz   = in_sizes[4];             // 1600000
    const int nb    = (nrows + BROW - 1) / BROW;   // 782 buckets

    // workspace layout (16B-aligned blocks)
    size_t off_wbf = 0;                                              // 32 KB
    size_t off_xp  = 65536;
    size_t xp_b    = (size_t)nrows * N_OUT_CH * 2;                   // Xp bf16: 12.8 MB
    size_t off_bc  = off_xp + ((xp_b + 15) & ~(size_t)15);           // bcur[nb] + ovfcnt
    size_t off_ov  = off_bc + (((size_t)(nb + 1) * 4 + 15) & ~(size_t)15);  // ovf int4
    size_t off_cv  = off_ov + (size_t)OVFCAP * 16;                   // colbuf padded
    size_t need    = off_cv + (size_t)nb * ECAP * 8;                 // 25.6 MB

    ushort* Wbf = (ushort*)((char*)d_ws + off_wbf);
    ushort* Xp  = (ushort*)((char*)d_ws + off_xp);

    wbf_kernel<<<(N_OUT_CH * N_IN_CH + 255) / 256, 256, 0, stream>>>(W, Wbf);
    {
        int ntiles = (nrows + 15) >> 4;
        int grid = GEMM_GRID;
        int maxg = (ntiles + 3) / 4;          // never launch idle blocks
        if (grid > maxg) grid = maxg;
        mfma_gemm_kernel<<<grid, 256, 0, stream>>>(X, Wbf, Xp, nrows);
    }

    if (ws_size >= need && nb <= NBK) {
        int*  bcur   = (int*)((char*)d_ws + off_bc);      // [nb] cursors
        int*  ovfcnt = bcur + nb;                          // 1 int
        int4* ovf    = (int4*)((char*)d_ws + off_ov);
        int2* colbuf = (int2*)((char*)d_ws + off_cv);

        hipMemsetAsync(bcur, 0, (size_t)(nb + 1) * 4, stream);
        bin_kernel<<<(nnz + B1_E - 1) / B1_E, 1024, 0, stream>>>(L_rows, L_cols, L_vals,
                bcur, ovfcnt, ovf, colbuf, nnz, nb);
        bspmm_kernel<<<nb, 512, 0, stream>>>(bcur, colbuf, Xp, out, nrows);
        ovf_kernel<<<16, 256, 0, stream>>>(ovfcnt, ovf, Xp, out);
    } else {
        hipMemsetAsync(d_out, 0, (size_t)out_size * sizeof(float), stream);
        long long total = (long long)nnz * 64;
        spmm_atomic_kernel<<<(int)((total + 255) / 256), 256, 0, stream>>>(
            L_rows, L_cols, L_vals, Xp, out, nnz);
    }
}

// Round 7
// 250.139 us; speedup vs baseline: 3.8099x; 1.0277x over previous
//
#include <hip/hip_runtime.h>

#define N_IN_CH 256
#define N_OUT_CH 64
#define XPAD 264      // 256 + 8 ushort pad: b128 LDS reads spread evenly over banks
#define BROW 128      // rows per bucket
#define NBK 1024      // max buckets: ceil(100000/128) = 782
#define B1_T 512      // bin_kernel threads
#define B1_E 4096     // edges per bin_kernel block (512 thr x 8 edges)
#define ECAP 4096     // edges per padded bucket region AND LDS buffer (mean 2048, 45-sigma)
#define OVFCAP 65536  // overflow edge capacity (never hit for uniform rows)
#define GEMM_GRID 768 // persistent GEMM blocks: 3/CU

typedef __attribute__((ext_vector_type(8))) short short8;
typedef __attribute__((ext_vector_type(4))) float f32x4;

__device__ inline ushort f2bf(float f) {
    unsigned u = __float_as_uint(f);
    return (ushort)((u + 0x7FFFu + ((u >> 16) & 1u)) >> 16);   // RTNE
}
__device__ inline float bf2f(ushort u) {
    return __uint_as_float(((unsigned)u) << 16);
}

// --- Kernel 1: persistent pipelined MFMA GEMM (Xp = X @ W^T).
//     W staged fp32->bf16 directly into LDS (wbf kernel folded in); block 0
//     also zeroes the bin cursors (memset dispatch folded in).
//     Each wave grid-strides over 16-row tiles with A-prefetch double-buffer:
//     convert raw(t), issue raw(t+1) global loads, compute t from regs+LDS
//     (B-reads on lgkmcnt, decoupled from the A-prefetch's vmcnt). ---
__global__ __launch_bounds__(256) void mfma_gemm_kernel(const float* __restrict__ X,
        const float* __restrict__ W, ushort* __restrict__ Xp, int nrows,
        int* __restrict__ zbuf, int nzero) {
    __shared__ ushort Ws[64 * XPAD];   // 33.8 KB
    const int tid = threadIdx.x;

    if (blockIdx.x == 0) {
        for (int i = tid; i < nzero; i += 256) zbuf[i] = 0;
    }

    #pragma unroll
    for (int it = 0; it < 16; ++it) {
        int f = it * 256 + tid;
        int n = f >> 6, c4 = f & 63;
        float4 w = *(const float4*)&W[n * N_IN_CH + c4 * 4];
        ushort4 u;
        u.x = f2bf(w.x); u.y = f2bf(w.y); u.z = f2bf(w.z); u.w = f2bf(w.w);
        *(ushort4*)&Ws[n * XPAD + c4 * 4] = u;
    }
    __syncthreads();

    const int wave = tid >> 6, lane = tid & 63;
    const int ml = lane & 15, q = lane >> 4;
    const int ntiles = (nrows + 15) >> 4;
    const int nw = gridDim.x * 4;
    int t = blockIdx.x * 4 + wave;

    const ushort* wsb = &Ws[ml * XPAD + q * 8];

    float4 raw[16];

#define ISSUE_TILE(tt)                                                     \
    do {                                                                   \
        int gr_ = (tt) * 16 + ml;                                          \
        if (gr_ < nrows) {                                                 \
            const float* xr_ = X + (size_t)gr_ * N_IN_CH + q * 8;          \
            _Pragma("unroll")                                              \
            for (int kt_ = 0; kt_ < 8; ++kt_) {                            \
                raw[2 * kt_]     = *(const float4*)&xr_[kt_ * 32];         \
                raw[2 * kt_ + 1] = *(const float4*)&xr_[kt_ * 32 + 4];     \
            }                                                              \
        } else {                                                           \
            _Pragma("unroll")                                              \
            for (int i_ = 0; i_ < 16; ++i_)                                \
                raw[i_] = make_float4(0.f, 0.f, 0.f, 0.f);                 \
        }                                                                  \
    } while (0)

    if (t < ntiles) ISSUE_TILE(t);

    while (t < ntiles) {
        short8 a[8];
        #pragma unroll
        for (int kt = 0; kt < 8; ++kt) {
            float4 f0 = raw[2 * kt], f1 = raw[2 * kt + 1];
            short8 s;
            s[0] = (short)f2bf(f0.x); s[1] = (short)f2bf(f0.y);
            s[2] = (short)f2bf(f0.z); s[3] = (short)f2bf(f0.w);
            s[4] = (short)f2bf(f1.x); s[5] = (short)f2bf(f1.y);
            s[6] = (short)f2bf(f1.z); s[7] = (short)f2bf(f1.w);
            a[kt] = s;
        }
        int tn = t + nw;
        if (tn < ntiles) ISSUE_TILE(tn);   // in flight across the whole compute

        #pragma unroll
        for (int nt = 0; nt < 4; ++nt) {
            f32x4 acc = {0.f, 0.f, 0.f, 0.f};
            #pragma unroll
            for (int kt = 0; kt < 8; ++kt) {
                short8 b = *(const short8*)&wsb[nt * 16 * XPAD + kt * 32];
                acc = __builtin_amdgcn_mfma_f32_16x16x32_bf16(a[kt], b, acc, 0, 0, 0);
            }
            // C/D: col = lane&15 (n within tile), row = q*4+reg (m within tile)
            #pragma unroll
            for (int reg = 0; reg < 4; ++reg) {
                int gr = t * 16 + q * 4 + reg;
                if (gr < nrows)
                    Xp[(size_t)gr * N_OUT_CH + nt * 16 + ml] = f2bf(acc[reg]);
            }
        }
        t = tn;
    }
#undef ISSUE_TILE
}

// --- B1: single-pass bin-append into PADDED bucket regions (b*ECAP).
//     512 threads x 8 edges: 391 blocks, up to 4 blocks/CU co-resident
//     (R6: 1024-thr blocks capped at 2/CU) and 8-deep load ILP.
//     LDS count -> 1 global atomic per bucket -> contiguous segment writes.
//     Overflowing edges (>=45-sigma, unreachable for uniform rows) go to the
//     overflow list, fixed up after bspmm. ---
__global__ __launch_bounds__(B1_T) void bin_kernel(const int* __restrict__ rows,
        const int* __restrict__ cols, const float* __restrict__ vals,
        int* __restrict__ bcur, int* __restrict__ ovfcnt, int4* __restrict__ ovf,
        int2* __restrict__ colbuf, int nnz, int nb) {
    __shared__ int cnt[NBK];
    __shared__ int base[NBK];
    const int t = threadIdx.x;

    for (int i = t; i < nb; i += B1_T) cnt[i] = 0;
    __syncthreads();

    const int e = blockIdx.x * B1_E + t * 8;
    int nval = nnz - e;
    if (nval > 8) nval = 8;
    if (nval < 0) nval = 0;

    int r[8], c[8]; float v[8];
    if (nval == 8) {
        *(int4*)&r[0] = *(const int4*)&rows[e];
        *(int4*)&r[4] = *(const int4*)&rows[e + 4];
        *(int4*)&c[0] = *(const int4*)&cols[e];
        *(int4*)&c[4] = *(const int4*)&cols[e + 4];
        *(float4*)&v[0] = *(const float4*)&vals[e];
        *(float4*)&v[4] = *(const float4*)&vals[e + 4];
    } else {
        #pragma unroll
        for (int j = 0; j < 8; ++j)
            if (j < nval) { r[j] = rows[e + j]; c[j] = cols[e + j]; v[j] = vals[e + j]; }
    }

    #pragma unroll
    for (int j = 0; j < 8; ++j)
        if (j < nval) atomicAdd(&cnt[r[j] >> 7], 1);
    __syncthreads();

    for (int i = t; i < nb; i += B1_T) {
        int cn = cnt[i];
        base[i] = cn ? atomicAdd(&bcur[i], cn) : 0;
        cnt[i] = 0;
    }
    __syncthreads();

    #pragma unroll
    for (int j = 0; j < 8; ++j) {
        if (j < nval) {
            int b = r[j] >> 7;
            int pib = base[b] + atomicAdd(&cnt[b], 1);
            if (pib < ECAP) {
                int2 cv;
                cv.x = c[j] | ((r[j] & 127) << 17);   // col < 2^17, row_local 7b
                cv.y = __float_as_int(v[j]);
                colbuf[(size_t)b * ECAP + pib] = cv;
            } else {
                int op = atomicAdd(ovfcnt, 1);
                if (op < OVFCAP) {
                    int4 o; o.x = r[j]; o.y = c[j];
                    o.z = __float_as_int(v[j]); o.w = 0;
                    ovf[op] = o;
                }
            }
        }
    }
}

// --- Fused bucket sort + SpMM: one block per bucket. Sort bucket's edges into
//     a 32 KB LDS buffer (int LDS atomics only — float LDS atomics are a CAS
//     loop, 10x slower, measured R2). Consume: each wave streams its 16 rows'
//     CONTIGUOUS ebuf range in 8-deep gather chunks with wave-uniform
//     row-change flushes (R6: per-row unroll-4 restarted the memory pipeline
//     every ~16 edges and held only 4 gathers in flight). ---
__global__ __launch_bounds__(512) void bspmm_kernel(const int* __restrict__ bcur,
        const int2* __restrict__ colbuf, const ushort* __restrict__ Xp,
        float* __restrict__ out, int nrows) {
    __shared__ int2 ebuf[ECAP];       // 32 KB
    __shared__ int rc[BROW];
    __shared__ int rb[BROW + 1];
    const int b = blockIdx.x, t = threadIdx.x;
    const int ne = min(bcur[b], ECAP);
    const int2* cb = colbuf + (size_t)b * ECAP;
    const int row0 = b * BROW;
    const int wave = t >> 6, lane = t & 63;

    if (t < BROW) rc[t] = 0;
    __syncthreads();
    for (int i = t; i < ne; i += 512)
        atomicAdd(&rc[(cb[i].x >> 17) & (BROW - 1)], 1);
    __syncthreads();
    int c0 = (t < BROW) ? rc[t] : 0;
    // inclusive Hillis-Steele scan over BROW entries
    #pragma unroll
    for (int d = 1; d < BROW; d <<= 1) {
        int a = (t < BROW && t >= d) ? rc[t - d] : 0;
        __syncthreads();
        if (t < BROW) rc[t] += a;
        __syncthreads();
    }
    if (t < BROW) rb[t] = rc[t] - c0;
    if (t == 0) rb[BROW] = ne;
    __syncthreads();
    if (t < BROW) rc[t] = 0;
    __syncthreads();
    for (int i = t; i < ne; i += 512) {
        int2 cv = cb[i];
        int rl = (cv.x >> 17) & (BROW - 1);
        int pos = rb[rl] + atomicAdd(&rc[rl], 1);
        ebuf[pos] = cv;
    }
    __syncthreads();

    // consume: wave w owns rows [w*16, w*16+16) -> contiguous ebuf range
    const int r0 = wave * 16;
    const int s = rb[r0], e = rb[r0 + 16];
    float accv = 0.f;
    int cur = -1;
    int i = s;
    for (; i + 8 <= e; i += 8) {
        int2 cv[8];
        #pragma unroll
        for (int j = 0; j < 8; ++j) cv[j] = ebuf[i + j];
        float x[8];
        #pragma unroll
        for (int j = 0; j < 8; ++j)
            x[j] = bf2f(Xp[(size_t)(cv[j].x & 0x1FFFF) * N_OUT_CH + lane]);
        #pragma unroll
        for (int j = 0; j < 8; ++j) {
            int rl = (cv[j].x >> 17) & (BROW - 1);
            if (rl != cur) {                    // wave-uniform branch
                if (cur >= 0) out[(size_t)(row0 + cur) * N_OUT_CH + lane] = accv;
                cur = rl; accv = 0.f;
            }
            accv += __int_as_float(cv[j].y) * x[j];
        }
    }
    for (; i < e; ++i) {
        int2 cv = ebuf[i];
        int rl = (cv.x >> 17) & (BROW - 1);
        if (rl != cur) {
            if (cur >= 0) out[(size_t)(row0 + cur) * N_OUT_CH + lane] = accv;
            cur = rl; accv = 0.f;
        }
        accv += __int_as_float(cv.y) *
                bf2f(Xp[(size_t)(cv.x & 0x1FFFF) * N_OUT_CH + lane]);
    }
    if (cur >= 0) out[(size_t)(row0 + cur) * N_OUT_CH + lane] = accv;

    // zero-fill rows with no edges (rare: P ~ e^-16 per row)
    for (int r = r0; r < r0 + 16; ++r) {
        if (rb[r] == rb[r + 1]) {
            int gr = row0 + r;
            if (gr < nrows) out[(size_t)gr * N_OUT_CH + lane] = 0.f;
        }
    }
}

// --- Overflow fix-up: atomically add any edges that overflowed a bucket
//     region (normally zero; returns immediately). Runs after bspmm. ---
__global__ __launch_bounds__(256) void ovf_kernel(const int* __restrict__ ovfcnt,
        const int4* __restrict__ ovf, const ushort* __restrict__ Xp,
        float* __restrict__ out) {
    int n = min(ovfcnt[0], OVFCAP);
    int lane = threadIdx.x & 63;
    for (int e = blockIdx.x * 4 + (threadIdx.x >> 6); e < n; e += gridDim.x * 4) {
        int4 v = ovf[e];
        atomicAdd(&out[(size_t)v.x * N_OUT_CH + lane],
                  __int_as_float(v.z) * bf2f(Xp[(size_t)v.y * N_OUT_CH + lane]));
    }
}

// --- Fallback atomic SpMM (ws too small — not expected) ---
__global__ __launch_bounds__(256) void spmm_atomic_kernel(const int* __restrict__ rows,
        const int* __restrict__ cols, const float* __restrict__ vals,
        const ushort* __restrict__ Xp, float* __restrict__ out, int nnz) {
    int t = blockIdx.x * blockDim.x + threadIdx.x;
    int e = t >> 6;
    int c = t & 63;
    if (e < nnz) {
        atomicAdd(&out[(size_t)rows[e] * N_OUT_CH + c],
                  vals[e] * bf2f(Xp[(size_t)cols[e] * N_OUT_CH + c]));
    }
}

extern "C" void kernel_launch(void* const* d_in, const int* in_sizes, int n_in,
                              void* d_out, int out_size, void* d_ws, size_t ws_size,
                              hipStream_t stream) {
    const float* X      = (const float*)d_in[2];
    const float* W      = (const float*)d_in[3];
    const int*   L_rows = (const int*)d_in[4];
    const int*   L_cols = (const int*)d_in[5];
    const float* L_vals = (const float*)d_in[6];
    float* out = (float*)d_out;

    const int nrows = in_sizes[2] / N_IN_CH;   // 100000
    const int nnz   = in_sizes[4];             // 1600000
    const int nb    = (nrows + BROW - 1) / BROW;   // 782 buckets

    // workspace layout (16B-aligned blocks)
    size_t off_xp  = 0;
    size_t xp_b    = (size_t)nrows * N_OUT_CH * 2;                   // Xp bf16: 12.8 MB
    size_t off_bc  = off_xp + ((xp_b + 15) & ~(size_t)15);           // bcur[nb] + ovfcnt
    size_t off_ov  = off_bc + (((size_t)(nb + 1) * 4 + 15) & ~(size_t)15);  // ovf int4
    size_t off_cv  = off_ov + (size_t)OVFCAP * 16;                   // colbuf padded
    size_t need    = off_cv + (size_t)nb * ECAP * 8;                 // 25.6 MB

    ushort* Xp = (ushort*)((char*)d_ws + off_xp);
    const bool binned = (ws_size >= need && nb <= NBK);
    int* bcur = (int*)((char*)d_ws + off_bc);   // valid only if binned

    {
        int ntiles = (nrows + 15) >> 4;
        int grid = GEMM_GRID;
        int maxg = (ntiles + 3) / 4;          // never launch idle blocks
        if (grid > maxg) grid = maxg;
        mfma_gemm_kernel<<<grid, 256, 0, stream>>>(X, W, Xp, nrows,
                binned ? bcur : (int*)d_ws, binned ? nb + 1 : 0);
    }

    if (binned) {
        int*  ovfcnt = bcur + nb;                          // 1 int
        int4* ovf    = (int4*)((char*)d_ws + off_ov);
        int2* colbuf = (int2*)((char*)d_ws + off_cv);

        bin_kernel<<<(nnz + B1_E - 1) / B1_E, B1_T, 0, stream>>>(L_rows, L_cols, L_vals,
                bcur, ovfcnt, ovf, colbuf, nnz, nb);
        bspmm_kernel<<<nb, 512, 0, stream>>>(bcur, colbuf, Xp, out, nrows);
        ovf_kernel<<<16, 256, 0, stream>>>(ovfcnt, ovf, Xp, out);
    } else {
        hipMemsetAsync(d_out, 0, (size_t)out_size * sizeof(float), stream);
        long long total = (long long)nnz * 64;
        spmm_atomic_kernel<<<(int)((total + 255) / 256), 256, 0, stream>>>(
            L_rows, L_cols, L_vals, Xp, out, nnz);
    }
}

// Round 8
// 247.761 us; speedup vs baseline: 3.8464x; 1.0096x over previous
//
#include <hip/hip_runtime.h>

#define N_IN_CH 256
#define N_OUT_CH 64
#define XPAD 264      // 256 + 8 ushort pad: b128 LDS reads spread evenly over banks
#define BROW 128      // rows per bucket
#define NBK 1024      // max buckets: ceil(100000/128) = 782
#define B1_T 256      // bin-role threads (= fused block size)
#define B1_E 2048     // edges per bin-role block (256 thr x 8 edges)
#define ECAP 4096     // edges per padded bucket region AND LDS buffer (mean 2048, 45-sigma)
#define OVFCAP 65536  // overflow edge capacity (never hit for uniform rows)
#define NGEMM 512     // gemm-role blocks in the fused kernel

typedef __attribute__((ext_vector_type(8))) short short8;
typedef __attribute__((ext_vector_type(4))) float f32x4;

__device__ inline ushort f2bf(float f) {
    unsigned u = __float_as_uint(f);
    return (ushort)((u + 0x7FFFu + ((u >> 16) & 1u)) >> 16);   // RTNE
}
__device__ inline float bf2f(ushort u) {
    return __uint_as_float(((unsigned)u) << 16);
}

// --- Fused GEMM | bin kernel. gemm (X,W -> Xp) and bin (edges -> colbuf) are
//     data-independent and individually latency-bound on DIFFERENT resources
//     (MFMA + vector loads vs LDS atomics + scattered stores); block-role
//     split runs them concurrently so one hides inside the other.
//     Blocks [0, ngemm): persistent pipelined MFMA GEMM (W staged fp32->bf16
//     into LDS; B-reads on lgkmcnt decoupled from A-prefetch vmcnt; each wave
//     grid-strides 16-row tiles, issuing tile t+1's loads before computing t).
//     Blocks [ngemm, ...): bin-append into padded bucket regions (b*ECAP):
//     LDS count -> 1 global atomic per bucket -> contiguous segment writes;
//     overflow (>=45-sigma) to a list fixed up in bspmm's tail. ---
__global__ __launch_bounds__(256) void fused_kernel(const float* __restrict__ X,
        const float* __restrict__ W, ushort* __restrict__ Xp, int nrows, int ngemm,
        const int* __restrict__ rows, const int* __restrict__ cols,
        const float* __restrict__ vals, int* __restrict__ bcur,
        int* __restrict__ ovfcnt, int4* __restrict__ ovf,
        int2* __restrict__ colbuf, int nnz, int nb) {
    __shared__ union SM {
        ushort ws[64 * XPAD];                      // 33.8 KB (gemm role)
        struct { int cnt[NBK]; int base[NBK]; } b; // 8 KB (bin role)
    } sm;
    const int tid = threadIdx.x;

    if (blockIdx.x < ngemm) {
        // ================= GEMM role =================
        #pragma unroll
        for (int it = 0; it < 16; ++it) {
            int f = it * 256 + tid;
            int n = f >> 6, c4 = f & 63;
            float4 w = *(const float4*)&W[n * N_IN_CH + c4 * 4];
            ushort4 u;
            u.x = f2bf(w.x); u.y = f2bf(w.y); u.z = f2bf(w.z); u.w = f2bf(w.w);
            *(ushort4*)&sm.ws[n * XPAD + c4 * 4] = u;
        }
        __syncthreads();

        const int wave = tid >> 6, lane = tid & 63;
        const int ml = lane & 15, q = lane >> 4;
        const int ntiles = (nrows + 15) >> 4;
        const int nw = ngemm * 4;
        int t = blockIdx.x * 4 + wave;

        const ushort* wsb = &sm.ws[ml * XPAD + q * 8];

        float4 raw[16];

#define ISSUE_TILE(tt)                                                     \
        do {                                                               \
            int gr_ = (tt) * 16 + ml;                                      \
            if (gr_ < nrows) {                                             \
                const float* xr_ = X + (size_t)gr_ * N_IN_CH + q * 8;      \
                _Pragma("unroll")                                          \
                for (int kt_ = 0; kt_ < 8; ++kt_) {                        \
                    raw[2 * kt_]     = *(const float4*)&xr_[kt_ * 32];     \
                    raw[2 * kt_ + 1] = *(const float4*)&xr_[kt_ * 32 + 4]; \
                }                                                          \
            } else {                                                       \
                _Pragma("unroll")                                          \
                for (int i_ = 0; i_ < 16; ++i_)                            \
                    raw[i_] = make_float4(0.f, 0.f, 0.f, 0.f);             \
            }                                                              \
        } while (0)

        if (t < ntiles) ISSUE_TILE(t);

        while (t < ntiles) {
            short8 a[8];
            #pragma unroll
            for (int kt = 0; kt < 8; ++kt) {
                float4 f0 = raw[2 * kt], f1 = raw[2 * kt + 1];
                short8 s;
                s[0] = (short)f2bf(f0.x); s[1] = (short)f2bf(f0.y);
                s[2] = (short)f2bf(f0.z); s[3] = (short)f2bf(f0.w);
                s[4] = (short)f2bf(f1.x); s[5] = (short)f2bf(f1.y);
                s[6] = (short)f2bf(f1.z); s[7] = (short)f2bf(f1.w);
                a[kt] = s;
            }
            int tn = t + nw;
            if (tn < ntiles) ISSUE_TILE(tn);   // in flight across the compute

            #pragma unroll
            for (int nt = 0; nt < 4; ++nt) {
                f32x4 acc = {0.f, 0.f, 0.f, 0.f};
                #pragma unroll
                for (int kt = 0; kt < 8; ++kt) {
                    short8 b = *(const short8*)&wsb[nt * 16 * XPAD + kt * 32];
                    acc = __builtin_amdgcn_mfma_f32_16x16x32_bf16(a[kt], b, acc, 0, 0, 0);
                }
                // C/D: col = lane&15 (n in tile), row = q*4+reg (m in tile)
                #pragma unroll
                for (int reg = 0; reg < 4; ++reg) {
                    int gr = t * 16 + q * 4 + reg;
                    if (gr < nrows)
                        Xp[(size_t)gr * N_OUT_CH + nt * 16 + ml] = f2bf(acc[reg]);
                }
            }
            t = tn;
        }
#undef ISSUE_TILE
    } else {
        // ================= bin role =================
        for (int i = tid; i < nb; i += B1_T) sm.b.cnt[i] = 0;
        __syncthreads();

        const int e = (blockIdx.x - ngemm) * B1_E + tid * 8;
        int nval = nnz - e;
        if (nval > 8) nval = 8;
        if (nval < 0) nval = 0;

        int r[8], c[8]; float v[8];
        if (nval == 8) {
            *(int4*)&r[0] = *(const int4*)&rows[e];
            *(int4*)&r[4] = *(const int4*)&rows[e + 4];
            *(int4*)&c[0] = *(const int4*)&cols[e];
            *(int4*)&c[4] = *(const int4*)&cols[e + 4];
            *(float4*)&v[0] = *(const float4*)&vals[e];
            *(float4*)&v[4] = *(const float4*)&vals[e + 4];
        } else {
            #pragma unroll
            for (int j = 0; j < 8; ++j)
                if (j < nval) { r[j] = rows[e + j]; c[j] = cols[e + j]; v[j] = vals[e + j]; }
        }

        #pragma unroll
        for (int j = 0; j < 8; ++j)
            if (j < nval) atomicAdd(&sm.b.cnt[r[j] >> 7], 1);
        __syncthreads();

        for (int i = tid; i < nb; i += B1_T) {
            int cn = sm.b.cnt[i];
            sm.b.base[i] = cn ? atomicAdd(&bcur[i], cn) : 0;
            sm.b.cnt[i] = 0;
        }
        __syncthreads();

        #pragma unroll
        for (int j = 0; j < 8; ++j) {
            if (j < nval) {
                int b = r[j] >> 7;
                int pib = sm.b.base[b] + atomicAdd(&sm.b.cnt[b], 1);
                if (pib < ECAP) {
                    int2 cv;
                    cv.x = c[j] | ((r[j] & 127) << 17);   // col < 2^17, row_local 7b
                    cv.y = __float_as_int(v[j]);
                    colbuf[(size_t)b * ECAP + pib] = cv;
                } else {
                    int op = atomicAdd(ovfcnt, 1);
                    if (op < OVFCAP) {
                        int4 o; o.x = r[j]; o.y = c[j];
                        o.z = __float_as_int(v[j]); o.w = 0;
                        ovf[op] = o;
                    }
                }
            }
        }
    }
}

// --- Fused bucket sort + SpMM: one block per bucket. Each thread holds its
//     8-edge contiguous colbuf chunk in registers (4x int4 loads; colbuf read
//     ONCE, R7 read it twice), hist/scan via int LDS atomics (float LDS
//     atomics are a CAS loop, 10x slower, measured R2), scatter to a sorted
//     32 KB LDS buffer, then each wave streams its 16 rows' contiguous range
//     in 8-deep gather chunks with wave-uniform row-change flushes.
//     Tail: drain the (normally empty) overflow list for this bucket. ---
__global__ __launch_bounds__(512) void bspmm_kernel(const int* __restrict__ bcur,
        const int2* __restrict__ colbuf, const ushort* __restrict__ Xp,
        float* __restrict__ out, int nrows, const int* __restrict__ ovfcnt,
        const int4* __restrict__ ovf) {
    __shared__ int2 ebuf[ECAP];       // 32 KB
    __shared__ int rc[BROW];
    __shared__ int rb[BROW + 1];
    const int b = blockIdx.x, t = threadIdx.x;
    const int ne = min(bcur[b], ECAP);
    const int2* cb = colbuf + (size_t)b * ECAP;
    const int row0 = b * BROW;
    const int wave = t >> 6, lane = t & 63;

    // load this thread's 8-edge chunk into registers (vectorized)
    int2 ev[8];
    const int ebase = t * 8;
    int ecnt = ne - ebase;
    if (ecnt > 8) ecnt = 8;
    if (ecnt < 0) ecnt = 0;
    if (ecnt == 8) {
        #pragma unroll
        for (int j = 0; j < 4; ++j)
            *(int4*)&ev[2 * j] = *(const int4*)&cb[ebase + 2 * j];
    } else {
        #pragma unroll
        for (int j = 0; j < 8; ++j)
            if (j < ecnt) ev[j] = cb[ebase + j];
    }

    if (t < BROW) rc[t] = 0;
    __syncthreads();
    #pragma unroll
    for (int j = 0; j < 8; ++j)
        if (j < ecnt) atomicAdd(&rc[(ev[j].x >> 17) & (BROW - 1)], 1);
    __syncthreads();
    int c0 = (t < BROW) ? rc[t] : 0;
    // inclusive Hillis-Steele scan over BROW entries
    #pragma unroll
    for (int d = 1; d < BROW; d <<= 1) {
        int a = (t < BROW && t >= d) ? rc[t - d] : 0;
        __syncthreads();
        if (t < BROW) rc[t] += a;
        __syncthreads();
    }
    if (t < BROW) rb[t] = rc[t] - c0;
    if (t == 0) rb[BROW] = ne;
    __syncthreads();
    if (t < BROW) rc[t] = 0;
    __syncthreads();
    #pragma unroll
    for (int j = 0; j < 8; ++j) {
        if (j < ecnt) {
            int rl = (ev[j].x >> 17) & (BROW - 1);
            int pos = rb[rl] + atomicAdd(&rc[rl], 1);
            ebuf[pos] = ev[j];
        }
    }
    __syncthreads();

    // consume: wave w owns rows [w*16, w*16+16) -> contiguous ebuf range
    const int r0 = wave * 16;
    const int s = rb[r0], e = rb[r0 + 16];
    float accv = 0.f;
    int cur = -1;
    int i = s;
    for (; i + 8 <= e; i += 8) {
        int2 cv[8];
        #pragma unroll
        for (int j = 0; j < 8; ++j) cv[j] = ebuf[i + j];
        float x[8];
        #pragma unroll
        for (int j = 0; j < 8; ++j)
            x[j] = bf2f(Xp[(size_t)(cv[j].x & 0x1FFFF) * N_OUT_CH + lane]);
        #pragma unroll
        for (int j = 0; j < 8; ++j) {
            int rl = (cv[j].x >> 17) & (BROW - 1);
            if (rl != cur) {                    // wave-uniform branch
                if (cur >= 0) out[(size_t)(row0 + cur) * N_OUT_CH + lane] = accv;
                cur = rl; accv = 0.f;
            }
            accv += __int_as_float(cv[j].y) * x[j];
        }
    }
    for (; i < e; ++i) {
        int2 cv = ebuf[i];
        int rl = (cv.x >> 17) & (BROW - 1);
        if (rl != cur) {
            if (cur >= 0) out[(size_t)(row0 + cur) * N_OUT_CH + lane] = accv;
            cur = rl; accv = 0.f;
        }
        accv += __int_as_float(cv.y) *
                bf2f(Xp[(size_t)(cv.x & 0x1FFFF) * N_OUT_CH + lane]);
    }
    if (cur >= 0) out[(size_t)(row0 + cur) * N_OUT_CH + lane] = accv;

    // zero-fill rows with no edges (rare: P ~ e^-16 per row)
    for (int r = r0; r < r0 + 16; ++r) {
        if (rb[r] == rb[r + 1]) {
            int gr = row0 + r;
            if (gr < nrows) out[(size_t)gr * N_OUT_CH + lane] = 0.f;
        }
    }

    // overflow tail: normally n==0 -> one broadcast load + exit
    __syncthreads();
    int n = min(ovfcnt[0], OVFCAP);
    for (int e2 = wave; e2 < n; e2 += 8) {
        int4 v = ovf[e2];
        if ((v.x >> 7) == b)
            atomicAdd(&out[(size_t)v.x * N_OUT_CH + lane],
                      __int_as_float(v.z) * bf2f(Xp[(size_t)v.y * N_OUT_CH + lane]));
    }
}

// --- Fallback atomic SpMM (ws too small — not expected) ---
__global__ __launch_bounds__(256) void spmm_atomic_kernel(const int* __restrict__ rows,
        const int* __restrict__ cols, const float* __restrict__ vals,
        const ushort* __restrict__ Xp, float* __restrict__ out, int nnz) {
    int t = blockIdx.x * blockDim.x + threadIdx.x;
    int e = t >> 6;
    int c = t & 63;
    if (e < nnz) {
        atomicAdd(&out[(size_t)rows[e] * N_OUT_CH + c],
                  vals[e] * bf2f(Xp[(size_t)cols[e] * N_OUT_CH + c]));
    }
}

extern "C" void kernel_launch(void* const* d_in, const int* in_sizes, int n_in,
                              void* d_out, int out_size, void* d_ws, size_t ws_size,
                              hipStream_t stream) {
    const float* X      = (const float*)d_in[2];
    const float* W      = (const float*)d_in[3];
    const int*   L_rows = (const int*)d_in[4];
    const int*   L_cols = (const int*)d_in[5];
    const float* L_vals = (const float*)d_in[6];
    float* out = (float*)d_out;

    const int nrows = in_sizes[2] / N_IN_CH;   // 100000
    const int nnz   = in_sizes[4];             // 1600000
    const int nb    = (nrows + BROW - 1) / BROW;   // 782 buckets

    // workspace layout (16B-aligned blocks)
    size_t off_xp  = 0;
    size_t xp_b    = (size_t)nrows * N_OUT_CH * 2;                   // Xp bf16: 12.8 MB
    size_t off_bc  = off_xp + ((xp_b + 15) & ~(size_t)15);           // bcur[nb] + ovfcnt
    size_t off_ov  = off_bc + (((size_t)(nb + 1) * 4 + 15) & ~(size_t)15);  // ovf int4
    size_t off_cv  = off_ov + (size_t)OVFCAP * 16;                   // colbuf padded
    size_t need    = off_cv + (size_t)nb * ECAP * 8;                 // 25.6 MB

    ushort* Xp = (ushort*)((char*)d_ws + off_xp);
    const bool binned = (ws_size >= need && nb <= NBK);
    int* bcur = (int*)((char*)d_ws + off_bc);

    int ntiles = (nrows + 15) >> 4;
    int ngemm = NGEMM;
    int maxg = (ntiles + 3) / 4;
    if (ngemm > maxg) ngemm = maxg;

    if (binned) {
        int*  ovfcnt = bcur + nb;                          // 1 int
        int4* ovf    = (int4*)((char*)d_ws + off_ov);
        int2* colbuf = (int2*)((char*)d_ws + off_cv);
        int nbin = (nnz + B1_E - 1) / B1_E;

        hipMemsetAsync(bcur, 0, (size_t)(nb + 1) * 4, stream);
        fused_kernel<<<ngemm + nbin, 256, 0, stream>>>(X, W, Xp, nrows, ngemm,
                L_rows, L_cols, L_vals, bcur, ovfcnt, ovf, colbuf, nnz, nb);
        bspmm_kernel<<<nb, 512, 0, stream>>>(bcur, colbuf, Xp, out, nrows, ovfcnt, ovf);
    } else {
        fused_kernel<<<ngemm, 256, 0, stream>>>(X, W, Xp, nrows, ngemm,
                nullptr, nullptr, nullptr, nullptr, nullptr, nullptr, nullptr, 0, 0);
        hipMemsetAsync(d_out, 0, (size_t)out_size * sizeof(float), stream);
        long long total = (long long)nnz * 64;
        spmm_atomic_kernel<<<(int)((total + 255) / 256), 256, 0, stream>>>(
            L_rows, L_cols, L_vals, Xp, out, nnz);
    }
}

// Round 9
// 242.041 us; speedup vs baseline: 3.9374x; 1.0236x over previous
//
#include <hip/hip_runtime.h>

#define N_IN_CH 256
#define N_OUT_CH 64
#define XPAD 264      // 256 + 8 ushort pad: b128 LDS reads spread evenly over banks
#define BROW 128      // rows per bucket
#define NBK 1024      // max buckets: ceil(100000/128) = 782
#define B1_T 256      // bin-role threads (= fused block size)
#define B1_E 2048     // edges per bin-role block (256 thr x 8 edges)
#define ECAP 4096     // edges per padded bucket region AND LDS buffer (mean 2048, 45-sigma)
#define OVFCAP 65536  // overflow edge capacity (never hit for uniform rows)
#define NGEMM 512     // gemm-role blocks in the fused kernel

typedef __attribute__((ext_vector_type(8))) short short8;
typedef __attribute__((ext_vector_type(4))) float f32x4;

__device__ inline ushort f2bf(float f) {
    unsigned u = __float_as_uint(f);
    return (ushort)((u + 0x7FFFu + ((u >> 16) & 1u)) >> 16);   // RTNE
}
__device__ inline float bf2f(ushort u) {
    return __uint_as_float(((unsigned)u) << 16);
}

// --- Fused GEMM | bin kernel (unchanged from R8; measured 68 us). ---
__global__ __launch_bounds__(256) void fused_kernel(const float* __restrict__ X,
        const float* __restrict__ W, ushort* __restrict__ Xp, int nrows, int ngemm,
        const int* __restrict__ rows, const int* __restrict__ cols,
        const float* __restrict__ vals, int* __restrict__ bcur,
        int* __restrict__ ovfcnt, int4* __restrict__ ovf,
        int2* __restrict__ colbuf, int nnz, int nb) {
    __shared__ union SM {
        ushort ws[64 * XPAD];                      // 33.8 KB (gemm role)
        struct { int cnt[NBK]; int base[NBK]; } b; // 8 KB (bin role)
    } sm;
    const int tid = threadIdx.x;

    if (blockIdx.x < ngemm) {
        // ================= GEMM role =================
        #pragma unroll
        for (int it = 0; it < 16; ++it) {
            int f = it * 256 + tid;
            int n = f >> 6, c4 = f & 63;
            float4 w = *(const float4*)&W[n * N_IN_CH + c4 * 4];
            ushort4 u;
            u.x = f2bf(w.x); u.y = f2bf(w.y); u.z = f2bf(w.z); u.w = f2bf(w.w);
            *(ushort4*)&sm.ws[n * XPAD + c4 * 4] = u;
        }
        __syncthreads();

        const int wave = tid >> 6, lane = tid & 63;
        const int ml = lane & 15, q = lane >> 4;
        const int ntiles = (nrows + 15) >> 4;
        const int nw = ngemm * 4;
        int t = blockIdx.x * 4 + wave;

        const ushort* wsb = &sm.ws[ml * XPAD + q * 8];

        float4 raw[16];

#define ISSUE_TILE(tt)                                                     \
        do {                                                               \
            int gr_ = (tt) * 16 + ml;                                      \
            if (gr_ < nrows) {                                             \
                const float* xr_ = X + (size_t)gr_ * N_IN_CH + q * 8;      \
                _Pragma("unroll")                                          \
                for (int kt_ = 0; kt_ < 8; ++kt_) {                        \
                    raw[2 * kt_]     = *(const float4*)&xr_[kt_ * 32];     \
                    raw[2 * kt_ + 1] = *(const float4*)&xr_[kt_ * 32 + 4]; \
                }                                                          \
            } else {                                                       \
                _Pragma("unroll")                                          \
                for (int i_ = 0; i_ < 16; ++i_)                            \
                    raw[i_] = make_float4(0.f, 0.f, 0.f, 0.f);             \
            }                                                              \
        } while (0)

        if (t < ntiles) ISSUE_TILE(t);

        while (t < ntiles) {
            short8 a[8];
            #pragma unroll
            for (int kt = 0; kt < 8; ++kt) {
                float4 f0 = raw[2 * kt], f1 = raw[2 * kt + 1];
                short8 s;
                s[0] = (short)f2bf(f0.x); s[1] = (short)f2bf(f0.y);
                s[2] = (short)f2bf(f0.z); s[3] = (short)f2bf(f0.w);
                s[4] = (short)f2bf(f1.x); s[5] = (short)f2bf(f1.y);
                s[6] = (short)f2bf(f1.z); s[7] = (short)f2bf(f1.w);
                a[kt] = s;
            }
            int tn = t + nw;
            if (tn < ntiles) ISSUE_TILE(tn);   // in flight across the compute

            #pragma unroll
            for (int nt = 0; nt < 4; ++nt) {
                f32x4 acc = {0.f, 0.f, 0.f, 0.f};
                #pragma unroll
                for (int kt = 0; kt < 8; ++kt) {
                    short8 b = *(const short8*)&wsb[nt * 16 * XPAD + kt * 32];
                    acc = __builtin_amdgcn_mfma_f32_16x16x32_bf16(a[kt], b, acc, 0, 0, 0);
                }
                // C/D: col = lane&15 (n in tile), row = q*4+reg (m in tile)
                #pragma unroll
                for (int reg = 0; reg < 4; ++reg) {
                    int gr = t * 16 + q * 4 + reg;
                    if (gr < nrows)
                        Xp[(size_t)gr * N_OUT_CH + nt * 16 + ml] = f2bf(acc[reg]);
                }
            }
            t = tn;
        }
#undef ISSUE_TILE
    } else {
        // ================= bin role =================
        for (int i = tid; i < nb; i += B1_T) sm.b.cnt[i] = 0;
        __syncthreads();

        const int e = (blockIdx.x - ngemm) * B1_E + tid * 8;
        int nval = nnz - e;
        if (nval > 8) nval = 8;
        if (nval < 0) nval = 0;

        int r[8], c[8]; float v[8];
        if (nval == 8) {
            *(int4*)&r[0] = *(const int4*)&rows[e];
            *(int4*)&r[4] = *(const int4*)&rows[e + 4];
            *(int4*)&c[0] = *(const int4*)&cols[e];
            *(int4*)&c[4] = *(const int4*)&cols[e + 4];
            *(float4*)&v[0] = *(const float4*)&vals[e];
            *(float4*)&v[4] = *(const float4*)&vals[e + 4];
        } else {
            #pragma unroll
            for (int j = 0; j < 8; ++j)
                if (j < nval) { r[j] = rows[e + j]; c[j] = cols[e + j]; v[j] = vals[e + j]; }
        }

        #pragma unroll
        for (int j = 0; j < 8; ++j)
            if (j < nval) atomicAdd(&sm.b.cnt[r[j] >> 7], 1);
        __syncthreads();

        for (int i = tid; i < nb; i += B1_T) {
            int cn = sm.b.cnt[i];
            sm.b.base[i] = cn ? atomicAdd(&bcur[i], cn) : 0;
            sm.b.cnt[i] = 0;
        }
        __syncthreads();

        #pragma unroll
        for (int j = 0; j < 8; ++j) {
            if (j < nval) {
                int b = r[j] >> 7;
                int pib = sm.b.base[b] + atomicAdd(&sm.b.cnt[b], 1);
                if (pib < ECAP) {
                    int2 cv;
                    cv.x = c[j] | ((r[j] & 127) << 17);   // col < 2^17, row_local 7b
                    cv.y = __float_as_int(v[j]);
                    colbuf[(size_t)b * ECAP + pib] = cv;
                } else {
                    int op = atomicAdd(ovfcnt, 1);
                    if (op < OVFCAP) {
                        int4 o; o.x = r[j]; o.y = c[j];
                        o.z = __float_as_int(v[j]); o.w = 0;
                        ovf[op] = o;
                    }
                }
            }
        }
    }
}

// --- Fused bucket sort + SpMM. Sort phase as R8 (register chunks, int LDS
//     atomics, sorted 32 KB ebuf). Consume phase REDESIGNED (R8 post-mortem:
//     gather core was VMEM-instruction-bound — 262 instrs/wave at 128 B each):
//     quarter-wave (16 lanes) per edge, lane = 4 channels (ushort4, 8 B/lane).
//     Each quarter owns a disjoint 4-row slice (accumulators never alias an
//     out row across quarters), streams its contiguous ebuf range in 4-deep
//     batches: ~65 gather instrs/wave at 512 B each. Flush = float4 store
//     (quarter-uniform branch). ---
__global__ __launch_bounds__(512) void bspmm_kernel(const int* __restrict__ bcur,
        const int2* __restrict__ colbuf, const ushort* __restrict__ Xp,
        float* __restrict__ out, int nrows, const int* __restrict__ ovfcnt,
        const int4* __restrict__ ovf) {
    __shared__ int2 ebuf[ECAP];       // 32 KB
    __shared__ int rc[BROW];
    __shared__ int rb[BROW + 1];
    const int b = blockIdx.x, t = threadIdx.x;
    const int ne = min(bcur[b], ECAP);
    const int2* cb = colbuf + (size_t)b * ECAP;
    const int row0 = b * BROW;

    // ---- sort phase ----
    int2 ev[8];
    const int ebase = t * 8;
    int ecnt = ne - ebase;
    if (ecnt > 8) ecnt = 8;
    if (ecnt < 0) ecnt = 0;
    if (ecnt == 8) {
        #pragma unroll
        for (int j = 0; j < 4; ++j)
            *(int4*)&ev[2 * j] = *(const int4*)&cb[ebase + 2 * j];
    } else {
        #pragma unroll
        for (int j = 0; j < 8; ++j)
            if (j < ecnt) ev[j] = cb[ebase + j];
    }

    if (t < BROW) rc[t] = 0;
    __syncthreads();
    #pragma unroll
    for (int j = 0; j < 8; ++j)
        if (j < ecnt) atomicAdd(&rc[(ev[j].x >> 17) & (BROW - 1)], 1);
    __syncthreads();
    int c0 = (t < BROW) ? rc[t] : 0;
    #pragma unroll
    for (int d = 1; d < BROW; d <<= 1) {
        int a = (t < BROW && t >= d) ? rc[t - d] : 0;
        __syncthreads();
        if (t < BROW) rc[t] += a;
        __syncthreads();
    }
    if (t < BROW) rb[t] = rc[t] - c0;
    if (t == 0) rb[BROW] = ne;
    __syncthreads();
    if (t < BROW) rc[t] = 0;
    __syncthreads();
    #pragma unroll
    for (int j = 0; j < 8; ++j) {
        if (j < ecnt) {
            int rl = (ev[j].x >> 17) & (BROW - 1);
            int pos = rb[rl] + atomicAdd(&rc[rl], 1);
            ebuf[pos] = ev[j];
        }
    }
    __syncthreads();

    // ---- consume phase: quarter (16 lanes) per 4-row group ----
    const int wave = t >> 6;
    const int q4 = (t >> 4) & 3;       // quarter within wave
    const int l16 = t & 15;            // lane within quarter; ch = l16*4
    const int qr0 = wave * 16 + q4 * 4;   // first local row of this quarter
    int i = rb[qr0];
    const int e = rb[qr0 + 4];
    float4 acc = make_float4(0.f, 0.f, 0.f, 0.f);
    int cur = -1;

    for (; i + 4 <= e; i += 4) {
        int2 cv[4];
        #pragma unroll
        for (int j = 0; j < 4; ++j) cv[j] = ebuf[i + j];
        ushort4 xv[4];
        #pragma unroll
        for (int j = 0; j < 4; ++j)
            xv[j] = *(const ushort4*)&Xp[(size_t)(cv[j].x & 0x1FFFF) * N_OUT_CH + l16 * 4];
        #pragma unroll
        for (int j = 0; j < 4; ++j) {
            int rl = (cv[j].x >> 17) & (BROW - 1);
            if (rl != cur) {                    // quarter-uniform branch
                if (cur >= 0)
                    *(float4*)&out[(size_t)(row0 + cur) * N_OUT_CH + l16 * 4] = acc;
                cur = rl;
                acc = make_float4(0.f, 0.f, 0.f, 0.f);
            }
            float vv = __int_as_float(cv[j].y);
            acc.x += vv * bf2f(xv[j].x);
            acc.y += vv * bf2f(xv[j].y);
            acc.z += vv * bf2f(xv[j].z);
            acc.w += vv * bf2f(xv[j].w);
        }
    }
    for (; i < e; ++i) {
        int2 cv = ebuf[i];
        int rl = (cv.x >> 17) & (BROW - 1);
        if (rl != cur) {
            if (cur >= 0)
                *(float4*)&out[(size_t)(row0 + cur) * N_OUT_CH + l16 * 4] = acc;
            cur = rl;
            acc = make_float4(0.f, 0.f, 0.f, 0.f);
        }
        ushort4 xv = *(const ushort4*)&Xp[(size_t)(cv.x & 0x1FFFF) * N_OUT_CH + l16 * 4];
        float vv = __int_as_float(cv.y);
        acc.x += vv * bf2f(xv.x);
        acc.y += vv * bf2f(xv.y);
        acc.z += vv * bf2f(xv.z);
        acc.w += vv * bf2f(xv.w);
    }
    if (cur >= 0)
        *(float4*)&out[(size_t)(row0 + cur) * N_OUT_CH + l16 * 4] = acc;

    // zero-fill this quarter's empty rows (rare: P ~ e^-16 per row)
    #pragma unroll
    for (int r = 0; r < 4; ++r) {
        int lr = qr0 + r;
        if (rb[lr] == rb[lr + 1]) {
            int gr = row0 + lr;
            if (gr < nrows)
                *(float4*)&out[(size_t)gr * N_OUT_CH + l16 * 4] =
                    make_float4(0.f, 0.f, 0.f, 0.f);
        }
    }

    // overflow tail: normally n==0 -> one broadcast load + exit
    __syncthreads();
    const int lane = t & 63;
    int n = min(ovfcnt[0], OVFCAP);
    for (int e2 = wave; e2 < n; e2 += 8) {
        int4 v = ovf[e2];
        if ((v.x >> 7) == b)
            atomicAdd(&out[(size_t)v.x * N_OUT_CH + lane],
                      __int_as_float(v.z) * bf2f(Xp[(size_t)v.y * N_OUT_CH + lane]));
    }
}

// --- Fallback atomic SpMM (ws too small — not expected) ---
__global__ __launch_bounds__(256) void spmm_atomic_kernel(const int* __restrict__ rows,
        const int* __restrict__ cols, const float* __restrict__ vals,
        const ushort* __restrict__ Xp, float* __restrict__ out, int nnz) {
    int t = blockIdx.x * blockDim.x + threadIdx.x;
    int e = t >> 6;
    int c = t & 63;
    if (e < nnz) {
        atomicAdd(&out[(size_t)rows[e] * N_OUT_CH + c],
                  vals[e] * bf2f(Xp[(size_t)cols[e] * N_OUT_CH + c]));
    }
}

extern "C" void kernel_launch(void* const* d_in, const int* in_sizes, int n_in,
                              void* d_out, int out_size, void* d_ws, size_t ws_size,
                              hipStream_t stream) {
    const float* X      = (const float*)d_in[2];
    const float* W      = (const float*)d_in[3];
    const int*   L_rows = (const int*)d_in[4];
    const int*   L_cols = (const int*)d_in[5];
    const float* L_vals = (const float*)d_in[6];
    float* out = (float*)d_out;

    const int nrows = in_sizes[2] / N_IN_CH;   // 100000
    const int nnz   = in_sizes[4];             // 1600000
    const int nb    = (nrows + BROW - 1) / BROW;   // 782 buckets

    // workspace layout (16B-aligned blocks)
    size_t off_xp  = 0;
    size_t xp_b    = (size_t)nrows * N_OUT_CH * 2;                   // Xp bf16: 12.8 MB
    size_t off_bc  = off_xp + ((xp_b + 15) & ~(size_t)15);           // bcur[nb] + ovfcnt
    size_t off_ov  = off_bc + (((size_t)(nb + 1) * 4 + 15) & ~(size_t)15);  // ovf int4
    size_t off_cv  = off_ov + (size_t)OVFCAP * 16;                   // colbuf padded
    size_t need    = off_cv + (size_t)nb * ECAP * 8;                 // 25.6 MB

    ushort* Xp = (ushort*)((char*)d_ws + off_xp);
    const bool binned = (ws_size >= need && nb <= NBK);
    int* bcur = (int*)((char*)d_ws + off_bc);

    int ntiles = (nrows + 15) >> 4;
    int ngemm = NGEMM;
    int maxg = (ntiles + 3) / 4;
    if (ngemm > maxg) ngemm = maxg;

    if (binned) {
        int*  ovfcnt = bcur + nb;                          // 1 int
        int4* ovf    = (int4*)((char*)d_ws + off_ov);
        int2* colbuf = (int2*)((char*)d_ws + off_cv);
        int nbin = (nnz + B1_E - 1) / B1_E;

        hipMemsetAsync(bcur, 0, (size_t)(nb + 1) * 4, stream);
        fused_kernel<<<ngemm + nbin, 256, 0, stream>>>(X, W, Xp, nrows, ngemm,
                L_rows, L_cols, L_vals, bcur, ovfcnt, ovf, colbuf, nnz, nb);
        bspmm_kernel<<<nb, 512, 0, stream>>>(bcur, colbuf, Xp, out, nrows, ovfcnt, ovf);
    } else {
        fused_kernel<<<ngemm, 256, 0, stream>>>(X, W, Xp, nrows, ngemm,
                nullptr, nullptr, nullptr, nullptr, nullptr, nullptr, nullptr, 0, 0);
        hipMemsetAsync(d_out, 0, (size_t)out_size * sizeof(float), stream);
        long long total = (long long)nnz * 64;
        spmm_atomic_kernel<<<(int)((total + 255) / 256), 256, 0, stream>>>(
            L_rows, L_cols, L_vals, Xp, out, nnz);
    }
}